// Round 13
// baseline (506.446 us; speedup 1.0000x reference)
//
#include <hip/hip_runtime.h>
#include <hip/hip_bf16.h>

#define NUM_ENT   50000
#define NUM_RELC  500
#define KTOP      50
#define EMB       400
#define FEAT      1000
#define N_NODES   50500
#define N_EDGES   400000
#define BATCH     4096
#define RELM1     499     // NUM_REL - 1

// padded GEMM dims
#define KP   1024         // FEAT padded to mult of 64
#define MP   50560        // N_NODES padded to 395*128
#define NP   512          // EMB padded to mult of 128

#define NB_SCAN ((N_NODES + 255) / 256)   // 198
#define NB_HIST ((N_EDGES + 255) / 256)   // 1563
#define NBIG    ((MP / 128) * 3)          // 1185

typedef __attribute__((ext_vector_type(8))) short short8;
typedef __attribute__((ext_vector_type(4))) float f32x4;

__device__ __forceinline__ ushort f2bf(float x) {
    __hip_bfloat16 h = __float2bfloat16(x);
    return *reinterpret_cast<ushort*>(&h);
}
__device__ __forceinline__ float bflo(uint u) { return __uint_as_float(u << 16); }
__device__ __forceinline__ float bfhi(uint u) { return __uint_as_float(u & 0xffff0000u); }

// ---- agent-scope sync helpers (rocPRIM-lookback-style, multi-XCD safe) ------
__device__ __forceinline__ void wait_ge(int* p, int target) {
    while (__hip_atomic_load(p, __ATOMIC_ACQUIRE, __HIP_MEMORY_SCOPE_AGENT) < target)
        __builtin_amdgcn_s_sleep(2);
}
__device__ __forceinline__ void signal_add(int* p) {
    __hip_atomic_fetch_add(p, 1, __ATOMIC_RELEASE, __HIP_MEMORY_SCOPE_AGENT);
}
// sync[] indices
#define SY_TICKET 0
#define SY_SCAN   1
#define SY_RABF   2
#define SY_CARRY  3
#define SY_OFFS   4

// =================== mega1: copy_convert | prep ==============================
#define NCC      4096
#define PB_LOG   RELM1                      // 499 logits blocks
#define PB_TWA   (PB_LOG + 256)             // 16x16 tiles of Wa
#define PB_TW1   (PB_TWA + 128)             // 16x8 tiles of W1
#define PB_HIST  (PB_TW1 + NB_HIST)
#define PB_TOTAL (PB_HIST + 1)
__global__ void mega1_kernel(const float* __restrict__ nf, float* __restrict__ temp,
                             ushort* __restrict__ Abf,
                             const float* __restrict__ Wp, const float* __restrict__ bp,
                             float* __restrict__ logits,
                             const float* __restrict__ Wa, ushort* __restrict__ Watbf,
                             const float* __restrict__ W1, ushort* __restrict__ Btbf,
                             const int* __restrict__ edge_index, int* __restrict__ cnt,
                             const int* __restrict__ ra_edge, float* __restrict__ dinv_s,
                             int* __restrict__ offs_sm, int* __restrict__ es_sm) {
    __shared__ float tile[64][65];
    int blk = blockIdx.x, t = threadIdx.x;
    if (blk < NCC) {
        size_t idx = (size_t)blk * 256 + t;
        size_t stride = (size_t)NCC * 256;
        size_t total = (size_t)MP * KP / 8;
        for (; idx < total; idx += stride) {
            int row = (int)(idx >> 7);
            int kb  = (int)(idx & 127);
            if (row < N_NODES && kb < 125) {
                size_t off = (size_t)row * FEAT + kb * 8;
                float4 a = *(const float4*)&nf[off];
                float4 b = *(const float4*)&nf[off + 4];
                *(float4*)&temp[off]     = a;
                *(float4*)&temp[off + 4] = b;
                ushort v[8];
                v[0] = f2bf(a.x); v[1] = f2bf(a.y); v[2] = f2bf(a.z); v[3] = f2bf(a.w);
                v[4] = f2bf(b.x); v[5] = f2bf(b.y); v[6] = f2bf(b.z); v[7] = f2bf(b.w);
                *(uint4*)&Abf[idx * 8] = *(uint4*)v;
            } else {
                uint4 z = {0u, 0u, 0u, 0u};
                *(uint4*)&Abf[idx * 8] = z;
            }
        }
        return;
    }
    int b = blk - NCC;
    if (b < PB_LOG) {
        float* red = &tile[0][0];
        float s = 0.f;
        for (int k = t; k < FEAT; k += 256) s += nf[(size_t)b * FEAT + k] * Wp[k];
        red[t] = s; __syncthreads();
        for (int st = 128; st > 0; st >>= 1) { if (t < st) red[t] += red[t + st]; __syncthreads(); }
        if (t == 0) logits[b] = red[0] + bp[0];
    } else if (b < PB_TW1) {
        const float* src; ushort* dst; int K, N, bb;
        if (b < PB_TWA) { bb = b - PB_LOG; src = Wa; dst = Watbf; K = FEAT; N = FEAT; }
        else            { bb = b - PB_TWA; src = W1; dst = Btbf;  K = FEAT; N = EMB;  }
        int k0 = (bb & 15) * 64, n0 = (bb >> 4) * 64;
        int tx = t & 63, ty = t >> 6;
        for (int i = ty; i < 64; i += 4) {
            int k = k0 + i, n = n0 + tx;
            tile[i][tx] = (k < K && n < N) ? src[(size_t)k * N + n] : 0.f;
        }
        __syncthreads();
        for (int i = ty; i < 64; i += 4) {
            int n = n0 + i, k = k0 + tx;
            dst[(size_t)n * KP + k] = f2bf(tile[tx][i]);
        }
    } else if (b < PB_HIST) {
        int e = (b - PB_TW1) * 256 + t;
        if (e < N_EDGES) atomicAdd(&cnt[edge_index[N_EDGES + e]], 1);
    } else {
        __shared__ int c[128];
        __shared__ int o50[64];
        __shared__ int cur[64];
        if (t < 128) c[t] = 0;
        if (t < 64)  cur[t] = 0;
        __syncthreads();
        for (int e = t; e < 2000; e += 256) atomicAdd(&c[ra_edge[2000 + e]], 1);
        __syncthreads();
        if (t < 2 * KTOP) dinv_s[t] = rsqrtf((float)c[t] + 1.0f);
        if (t == 0) {
            int run = 0;
            for (int j = 0; j < KTOP; j++) { o50[j] = run; run += c[KTOP + j]; }
            o50[KTOP] = run;
        }
        __syncthreads();
        if (t < KTOP + 1) offs_sm[t] = o50[t];
        for (int e = t; e < 2000; e += 256) {
            int dst = ra_edge[2000 + e];
            if (dst >= KTOP) {
                int pos = o50[dst - KTOP] + atomicAdd(&cur[dst - KTOP], 1);
                es_sm[pos] = ra_edge[e];
            }
        }
    }
}

// =================== gemm body (device fn) ===================================
template <typename OutT, bool PACK5>
__device__ __forceinline__ void gemm_body(const ushort* __restrict__ A,
                                          const ushort* __restrict__ Bt,
                                          OutT* __restrict__ C,
                                          int M, int N, int ldc,
                                          int orig, int nwg,
                                          ushort* As, ushort* Bs, int t) {
    int q = nwg >> 3, r8 = nwg & 7;
    int xcd = orig & 7;
    int wgid = (xcd < r8 ? xcd * (q + 1) : r8 * (q + 1) + (xcd - r8) * q) + (orig >> 3);
    int ntiles = PACK5 ? 3 : ((N + 127) >> 7);
    int n0 = (wgid % ntiles) * 128;
    int m0 = (wgid / ntiles) * 128;

    int srow = t >> 3;
    int kbx  = (t & 7) ^ (srow & 7);
    int lane = t & 63;
    int wv   = t >> 6;
    int wr   = wv >> 1, wc = wv & 1;
    int l15  = lane & 15, lhi = lane >> 4;

    f32x4 acc[4][5];
    #pragma unroll
    for (int m = 0; m < 4; m++)
        #pragma unroll
        for (int n = 0; n < 5; n++) acc[m][n] = (f32x4){0.f, 0.f, 0.f, 0.f};

    for (int kt = 0; kt < KP / 64; kt++) {
        int k0 = kt * 64;
        #pragma unroll
        for (int r = 0; r < 4; r++) {
            int row = r * 32 + srow;
            const ushort* ga = A  + (size_t)(m0 + row) * KP + k0 + kbx * 8;
            const ushort* gb = Bt + (size_t)(n0 + row) * KP + k0 + kbx * 8;
            ushort* la = &As[(size_t)row * 64 + (t & 7) * 8];
            ushort* lb = &Bs[(size_t)row * 64 + (t & 7) * 8];
            __builtin_amdgcn_global_load_lds(
                (const __attribute__((address_space(1))) unsigned int*)ga,
                (__attribute__((address_space(3))) unsigned int*)la, 16, 0, 0);
            __builtin_amdgcn_global_load_lds(
                (const __attribute__((address_space(1))) unsigned int*)gb,
                (__attribute__((address_space(3))) unsigned int*)lb, 16, 0, 0);
        }
        if (PACK5) {
            if (n0 == 256 && t < 128) {
                int row = 128 + srow;
                const ushort* gb = Bt + (size_t)(n0 + row) * KP + k0 + kbx * 8;
                ushort* lb = &Bs[(size_t)row * 64 + (t & 7) * 8];
                __builtin_amdgcn_global_load_lds(
                    (const __attribute__((address_space(1))) unsigned int*)gb,
                    (__attribute__((address_space(3))) unsigned int*)lb, 16, 0, 0);
            }
        }
        __syncthreads();

        #pragma unroll
        for (int ks = 0; ks < 2; ks++) {
            int cswz = ((ks * 64 + lhi * 16) ^ ((lane & 7) << 4)) >> 1;
            short8 af[4], bfr[5];
            #pragma unroll
            for (int m = 0; m < 4; m++) {
                int rowl = wr * 64 + m * 16 + l15;
                af[m] = *(const short8*)&As[rowl * 64 + cswz];
            }
            #pragma unroll
            for (int n = 0; n < 5; n++) {
                bool valid = PACK5 ? ((n < 4) || (wc == 1 && n0 == 256))
                                   : ((n < 4) && (n0 + wc * 64 + n * 16 < N));
                if (valid) {
                    int rowl = wc * 64 + n * 16 + l15;
                    bfr[n] = *(const short8*)&Bs[rowl * 64 + cswz];
                }
            }
            #pragma unroll
            for (int m = 0; m < 4; m++)
                #pragma unroll
                for (int n = 0; n < 5; n++) {
                    bool valid = PACK5 ? ((n < 4) || (wc == 1 && n0 == 256))
                                       : ((n < 4) && (n0 + wc * 64 + n * 16 < N));
                    if (valid)
                        acc[m][n] = __builtin_amdgcn_mfma_f32_16x16x32_bf16(
                            af[m], bfr[n], acc[m][n], 0, 0, 0);
                }
        }
        __syncthreads();
    }

    #pragma unroll
    for (int m = 0; m < 4; m++) {
        #pragma unroll
        for (int n = 0; n < 5; n++) {
            bool valid = PACK5 ? ((n < 4) || (wc == 1 && n0 == 256))
                               : ((n < 4) && (n0 + wc * 64 + n * 16 < N));
            if (!valid) continue;
            int gc = n0 + wc * 64 + n * 16 + l15;
            if (gc >= N) continue;
            int gr0 = m0 + wr * 64 + m * 16 + lhi * 4;
            #pragma unroll
            for (int j = 0; j < 4; j++) {
                int gr = gr0 + j;
                if (gr < M) {
                    if constexpr (sizeof(OutT) == 2)
                        C[(size_t)gr * ldc + gc] = (OutT)f2bf(acc[m][n][j]);
                    else
                        C[(size_t)gr * ldc + gc] = (OutT)acc[m][n][j];
                }
            }
        }
    }
}

// =================== megaX: ticket-ordered fused middle ======================
// tickets: scan(198) | rabf(128) | carry(1) | offs-add(198) | gemm_big(1185) |
//          gemm_small(8, waits rabf) | fill_csr(1563, waits offs)
#define TK_RABF0 198
#define TK_CARRY 326
#define TK_OFFS0 327
#define TK_GBIG0 525
#define TK_GSM0  (TK_GBIG0 + NBIG)          // 1710
#define TK_CSR0  (TK_GSM0 + 8)              // 1718
#define TK_TOTAL (TK_CSR0 + NB_HIST)        // 3281
__global__ __launch_bounds__(256) void megaX_kernel(
        int* __restrict__ sync,
        const float* __restrict__ logits,
        const float* __restrict__ anchor, const float* __restrict__ nf,
        ushort* __restrict__ rabf, int* __restrict__ idxbuf, float* __restrict__ probsel,
        const int* __restrict__ cnt, int* __restrict__ offs,
        int* __restrict__ partials, float* __restrict__ dinv,
        const ushort* __restrict__ Abf, const ushort* __restrict__ Btbf,
        ushort* __restrict__ xwb,
        const ushort* __restrict__ Watbf, float* __restrict__ raw,
        const int* __restrict__ ei, int* __restrict__ cursor,
        int* __restrict__ esrc, float* __restrict__ ecoef) {
    __shared__ ushort As[128 * 64];
    __shared__ ushort Bs[144 * 64];
    __shared__ int tk_s;
    int t = threadIdx.x;
    if (t == 0) tk_s = atomicAdd(&sync[SY_TICKET], 1);
    __syncthreads();
    int tk = tk_s;

    if (tk < TK_RABF0) {
        // ---- scan_blocks: per-block exclusive scan of cnt + fused dinv ----
        int* s = (int*)As;
        int b = tk;
        int i = b * 256 + t;
        int v = (i < N_NODES) ? cnt[i] : 0;
        if (i < N_NODES) dinv[i] = rsqrtf((float)v + 1.0f);
        s[t] = v; __syncthreads();
        for (int off = 1; off < 256; off <<= 1) {
            int add = (t >= off) ? s[t - off] : 0;
            __syncthreads();
            s[t] += add;
            __syncthreads();
        }
        if (i < N_NODES) offs[i] = s[t] - v;
        if (t == 255) partials[b] = s[t];
        __syncthreads();
        if (t == 0) { __threadfence(); signal_add(&sync[SY_SCAN]); }
    } else if (tk < TK_CARRY) {
        // ---- rabf row (local top-k from logits) ----
        float* l   = (float*)As;            // 499
        float* p   = l + 512;               // 499
        int*   fl  = (int*)(l + 1024);      // 499
        float* red = l + 1536;              // 256
        __shared__ int   pick;
        __shared__ float pickp;
        int r = tk - TK_RABF0;
        float v1 = (t < RELM1) ? logits[t] : -1e30f;
        float v2 = (t + 256 < RELM1) ? logits[t + 256] : -1e30f;
        if (t < RELM1) l[t] = v1;
        if (t + 256 < RELM1) l[t + 256] = v2;
        red[t] = fmaxf(v1, v2); __syncthreads();
        for (int s = 128; s > 0; s >>= 1) { if (t < s) red[t] = fmaxf(red[t], red[t + s]); __syncthreads(); }
        float m = red[0]; __syncthreads();
        float e1 = (t < RELM1) ? expf(v1 - m) : 0.f;
        float e2 = (t + 256 < RELM1) ? expf(v2 - m) : 0.f;
        red[t] = e1 + e2; __syncthreads();
        for (int s = 128; s > 0; s >>= 1) { if (t < s) red[t] += red[t + s]; __syncthreads(); }
        float denom = red[0];
        if (t < RELM1) p[t] = e1 / denom;
        if (t + 256 < RELM1) p[t + 256] = e2 / denom;
        __syncthreads();
        #pragma unroll
        for (int h = 0; h < 2; h++) {
            int i = t + h * 256;
            if (i < RELM1) {
                float li = l[i]; int c = 0;
                for (int j = 0; j < RELM1; j++) {
                    float lj = l[j];
                    c += (lj > li) || (lj == li && j < i);
                }
                fl[i] = (c < KTOP) ? 1 : 0;
            }
        }
        __syncthreads();
        if (t == 0) pick = -1;
        __syncthreads();
        int want = r - KTOP;
        #pragma unroll
        for (int h = 0; h < 2; h++) {
            int i = t + h * 256;
            if (i < RELM1 && fl[i]) {
                int rank = 0;
                for (int j = 0; j < i; j++) rank += fl[j];
                if (r == 0) { idxbuf[rank] = i; probsel[rank] = p[i]; }
                if (rank == want) { pick = i; pickp = p[i]; }
            }
        }
        __syncthreads();
        const float* src = nullptr; float scale = 1.f;
        if (r < KTOP) { src = anchor + (size_t)r * FEAT; }
        else if (r < 2 * KTOP) { src = nf + (size_t)pick * FEAT; scale = pickp; }
        for (int k = t; k < KP; k += 256) {
            float v = (src != nullptr && k < FEAT) ? src[k] * scale : 0.f;
            rabf[(size_t)r * KP + k] = f2bf(v);
        }
        __syncthreads();
        if (t == 0) { __threadfence(); signal_add(&sync[SY_RABF]); }
    } else if (tk == TK_CARRY) {
        // ---- carry scan over partials (single block) ----
        wait_ge(&sync[SY_SCAN], NB_SCAN);
        int* s = (int*)As;
        int v = (t < NB_SCAN) ? partials[t] : 0;
        s[t] = v; __syncthreads();
        for (int off = 1; off < 256; off <<= 1) {
            int add = (t >= off) ? s[t - off] : 0;
            __syncthreads();
            s[t] += add;
            __syncthreads();
        }
        if (t < NB_SCAN) partials[t] = s[t] - v;   // exclusive carry
        __syncthreads();
        if (t == 0) { __threadfence(); signal_add(&sync[SY_CARRY]); }
    } else if (tk < TK_GBIG0) {
        // ---- offs += carry ----
        wait_ge(&sync[SY_CARRY], 1);
        int b = tk - TK_OFFS0;
        int carry = partials[b];
        int i = b * 256 + t;
        if (i < N_NODES && carry) offs[i] += carry;
        __syncthreads();
        if (t == 0) { __threadfence(); signal_add(&sync[SY_OFFS]); }
    } else if (tk < TK_GSM0) {
        gemm_body<ushort, true>(Abf, Btbf, xwb, N_NODES, EMB, EMB,
                                tk - TK_GBIG0, NBIG, As, Bs, t);
    } else if (tk < TK_CSR0) {
        wait_ge(&sync[SY_RABF], 128);
        gemm_body<float, false>(rabf, Watbf, raw, 2 * KTOP, FEAT, FEAT,
                                tk - TK_GSM0, 8, As, Bs, t);
    } else {
        wait_ge(&sync[SY_OFFS], NB_SCAN);
        int e = (tk - TK_CSR0) * 256 + t;
        if (e >= N_EDGES) return;
        int src = ei[e], dst = ei[N_EDGES + e];
        int pos = offs[dst] + atomicAdd(&cursor[dst], 1);
        esrc[pos] = src;
        ecoef[pos] = dinv[src] * dinv[dst];
    }
}

// =================== fused epilogue: gather_big | gather_small | score =======
#define EB_GB ((N_NODES + 3) / 4)          // 12625 blocks: big gather
#define EB_GS (EB_GB + KTOP)               // +50: small gather into temp
#define EB_TOTAL (EB_GS + BATCH / 4)       // +1024: scoring
__global__ __launch_bounds__(256) void epilogue_kernel(
        const int* __restrict__ esrc, const float* __restrict__ ecoef,
        const int* __restrict__ offs, const int* __restrict__ cnt,
        const ushort* __restrict__ xwb, const float* __restrict__ dinv,
        const float* __restrict__ b1, float* __restrict__ x,
        const int* __restrict__ es_sm, const int* __restrict__ offs_sm,
        const float* __restrict__ raw, const float* __restrict__ dinv_s,
        const float* __restrict__ ba, const int* __restrict__ idxbuf,
        float* __restrict__ temp,
        const float* __restrict__ ent, const float* __restrict__ rel,
        const int* __restrict__ r_idx, const int* __restrict__ e1_idx,
        const int* __restrict__ e2_idx, const float* __restrict__ conv_w,
        const float* __restrict__ conv_b, const float* __restrict__ fc_w,
        const float* __restrict__ fc_b, float* __restrict__ out) {
    int blk = blockIdx.x, t = threadIdx.x;
    if (blk < EB_GB) {
        int wave = t >> 6, lane = t & 63;
        int dst = blk * 4 + wave;
        if (dst >= N_NODES) return;
        int start = offs[dst], deg = cnt[dst];
        bool act = lane < EMB / 8;
        float acc[8] = {};
        int j = 0;
        for (; j + 1 < deg; j += 2) {
            int s0 = esrc[start + j], s1 = esrc[start + j + 1];
            float c0 = ecoef[start + j], c1 = ecoef[start + j + 1];
            if (act) {
                uint4 u0 = *(const uint4*)(xwb + (size_t)s0 * EMB + lane * 8);
                uint4 u1 = *(const uint4*)(xwb + (size_t)s1 * EMB + lane * 8);
                acc[0] += bflo(u0.x) * c0 + bflo(u1.x) * c1;
                acc[1] += bfhi(u0.x) * c0 + bfhi(u1.x) * c1;
                acc[2] += bflo(u0.y) * c0 + bflo(u1.y) * c1;
                acc[3] += bfhi(u0.y) * c0 + bfhi(u1.y) * c1;
                acc[4] += bflo(u0.z) * c0 + bflo(u1.z) * c1;
                acc[5] += bfhi(u0.z) * c0 + bfhi(u1.z) * c1;
                acc[6] += bflo(u0.w) * c0 + bflo(u1.w) * c1;
                acc[7] += bfhi(u0.w) * c0 + bfhi(u1.w) * c1;
            }
        }
        if (j < deg) {
            int s0 = esrc[start + j];
            float c0 = ecoef[start + j];
            if (act) {
                uint4 u0 = *(const uint4*)(xwb + (size_t)s0 * EMB + lane * 8);
                acc[0] += bflo(u0.x) * c0; acc[1] += bfhi(u0.x) * c0;
                acc[2] += bflo(u0.y) * c0; acc[3] += bfhi(u0.y) * c0;
                acc[4] += bflo(u0.z) * c0; acc[5] += bfhi(u0.z) * c0;
                acc[6] += bflo(u0.w) * c0; acc[7] += bfhi(u0.w) * c0;
            }
        }
        if (!act) return;
        float d2 = dinv[dst] * dinv[dst];
        uint4 u = *(const uint4*)(xwb + (size_t)dst * EMB + lane * 8);
        const float* bp = b1 + lane * 8;
        float* xo = x + (size_t)dst * EMB + lane * 8;
        float4 o0, o1;
        o0.x = fmaxf(acc[0] + bflo(u.x) * d2 + bp[0], 0.f);
        o0.y = fmaxf(acc[1] + bfhi(u.x) * d2 + bp[1], 0.f);
        o0.z = fmaxf(acc[2] + bflo(u.y) * d2 + bp[2], 0.f);
        o0.w = fmaxf(acc[3] + bfhi(u.y) * d2 + bp[3], 0.f);
        o1.x = fmaxf(acc[4] + bflo(u.z) * d2 + bp[4], 0.f);
        o1.y = fmaxf(acc[5] + bfhi(u.z) * d2 + bp[5], 0.f);
        o1.z = fmaxf(acc[6] + bflo(u.w) * d2 + bp[6], 0.f);
        o1.w = fmaxf(acc[7] + bfhi(u.w) * d2 + bp[7], 0.f);
        *(float4*)&xo[0] = o0;
        *(float4*)&xo[4] = o1;
    } else if (blk < EB_GS) {
        int j = blk - EB_GB;
        int r = KTOP + j;
        int start = offs_sm[j], end = offs_sm[j + 1];
        float dr = dinv_s[r];
        float acc[4] = {};
        for (int p = start; p < end; p++) {
            int src = es_sm[p];
            float cc = dinv_s[src] * dr;
            const float* rs = raw + (size_t)src * FEAT;
            #pragma unroll
            for (int qq = 0; qq < 4; qq++) {
                int k = t + qq * 256;
                if (k < FEAT) acc[qq] += rs[k] * cc;
            }
        }
        float d2 = dr * dr;
        const float* rd = raw + (size_t)r * FEAT;
        float* to = temp + (size_t)idxbuf[j] * FEAT;
        #pragma unroll
        for (int qq = 0; qq < 4; qq++) {
            int k = t + qq * 256;
            if (k < FEAT) to[k] = fmaxf(acc[qq] + rd[k] * d2 + ba[k], 0.f);
        }
    } else {
        __shared__ float cw[24];
        __shared__ float cb[8];
        if (t < 24) cw[t] = conv_w[t];
        if (t < 8)  cb[t] = conv_b[t];
        __syncthreads();
        int wave = t >> 6, lane = t & 63;
        int b = (blk - EB_GS) * 4 + wave;
        if (b >= BATCH) return;
        const float* r  = rel + (size_t)r_idx[b] * EMB;
        const float* e1 = ent + (size_t)e1_idx[b] * EMB;
        const float* e2 = ent + (size_t)e2_idx[b] * EMB;
        float partial = 0.f;
        for (int p = lane; p < EMB; p += 64) {
            float c0 = r[p], c1 = e1[p], c2 = e2[p];
            for (int g = 0; g < 4; g++) {
                float h0 = c0 * cw[(2 * g) * 3 + 0] + c1 * cw[(2 * g) * 3 + 1] + c2 * cw[(2 * g) * 3 + 2] + cb[2 * g];
                float h1 = c0 * cw[(2 * g + 1) * 3 + 0] + c1 * cw[(2 * g + 1) * 3 + 1] + c2 * cw[(2 * g + 1) * 3 + 2] + cb[2 * g + 1];
                partial += fmaxf(h0, h1) * fc_w[g * EMB + p];
            }
        }
        for (int off = 32; off > 0; off >>= 1) partial += __shfl_down(partial, off, 64);
        if (lane == 0) out[b] = partial + fc_b[0];
    }
}

extern "C" void kernel_launch(void* const* d_in, const int* in_sizes, int n_in,
                              void* d_out, int out_size, void* d_ws, size_t ws_size,
                              hipStream_t stream) {
    const float* num_feature = (const float*)d_in[0];
    const float* anchor      = (const float*)d_in[1];
    const float* Wp          = (const float*)d_in[2];
    const float* bp          = (const float*)d_in[3];
    const float* Wa          = (const float*)d_in[4];
    const float* ba          = (const float*)d_in[5];
    const float* W1          = (const float*)d_in[6];
    const float* b1          = (const float*)d_in[7];
    const float* ent_emb     = (const float*)d_in[8];
    const float* rel_emb     = (const float*)d_in[9];
    const float* conv_w      = (const float*)d_in[10];
    const float* conv_b      = (const float*)d_in[11];
    const float* fc_w        = (const float*)d_in[12];
    const float* fc_b        = (const float*)d_in[13];
    const int*   edge_index  = (const int*)d_in[14];
    const int*   ra_edge     = (const int*)d_in[15];
    const int*   r_idx       = (const int*)d_in[16];
    const int*   e1_idx      = (const int*)d_in[17];
    const int*   e2_idx      = (const int*)d_in[18];

    float* out_score = (float*)d_out;                       // 4096
    float* out_x     = out_score + BATCH;                   // 50500*400
    float* out_temp  = out_x + (size_t)N_NODES * EMB;       // 50500*1000 floats

    // ---- all scratch in d_ws (~152 MB of ~1.13 GB) ----
    float* ws_f     = (float*)d_ws;
    float* logits   = ws_f;                          // 512
    int*   idxbuf   = (int*)(ws_f + 512);            // 64
    float* probsel  = ws_f + 576;                    // 64
    float* dinv_s   = ws_f + 640;                    // 128
    int*   offs_sm  = (int*)(ws_f + 768);            // 64
    int*   es_sm    = (int*)(ws_f + 832);            // 2048
    int*   sync     = (int*)(ws_f + 2880);           // 16
    float* raw      = ws_f + 2896;                   // 100,000
    float* dinv     = ws_f + 102896;                 // 50,500
    ushort* rabf    = (ushort*)(ws_f + 153396);      // 128*KP ushorts  (65,536 f)
    ushort* Btbf    = (ushort*)(ws_f + 218932);      // NP*KP ushorts   (262,144 f)
    ushort* Watbf   = (ushort*)(ws_f + 481076);      // KP*KP ushorts   (524,288 f)
    int*   cnt      = (int*)(ws_f + 1005364);        // 50,500
    int*   cursor   = cnt + N_NODES;                 // 50,500
    int*   offs     = cursor + N_NODES;              // 50,500
    int*   partials = offs + N_NODES;                // 256
    int*   esrc     = partials + 256;                // 400,000
    float* ecoef    = (float*)(esrc + N_EDGES);      // 400,000
    ushort* Abf     = (ushort*)(ecoef + N_EDGES);    // MP*KP ushorts (25,886,720 f)
    ushort* xwb     = Abf + (size_t)MP * KP;         // N_NODES*EMB ushorts
    // end ≈ 38.0M floats ≈ 152 MB

    hipMemsetAsync(cnt, 0, 2 * N_NODES * sizeof(int), stream);   // cnt + cursor
    hipMemsetAsync(sync, 0, 16 * sizeof(int), stream);

    // ---- mega1: temp-copy + A convert | logits | transposes | hist | smallCSR
    mega1_kernel<<<NCC + PB_TOTAL, 256, 0, stream>>>(
        num_feature, out_temp, Abf, Wp, bp, logits, Wa, Watbf, W1, Btbf,
        edge_index, cnt, ra_edge, dinv_s, offs_sm, es_sm);

    // ---- megaX: ticket-ordered scan | rabf | carry | offs | gemms | fill_csr
    megaX_kernel<<<TK_TOTAL, 256, 0, stream>>>(
        sync, logits, anchor, num_feature, rabf, idxbuf, probsel,
        cnt, offs, partials, dinv, Abf, Btbf, xwb, Watbf, raw,
        edge_index, cursor, esrc, ecoef);

    // ---- fused epilogue: big gather | small gather -> temp | scoring ----
    epilogue_kernel<<<EB_TOTAL, 256, 0, stream>>>(
        esrc, ecoef, offs, cnt, xwb, dinv, b1, out_x,
        es_sm, offs_sm, raw, dinv_s, ba, idxbuf, out_temp,
        ent_emb, rel_emb, r_idx, e1_idx, e2_idx, conv_w, conv_b, fc_w, fc_b,
        out_score);
}

// Round 14
// 370.182 us; speedup vs baseline: 1.3681x; 1.3681x over previous
//
#include <hip/hip_runtime.h>
#include <hip/hip_bf16.h>

#define NUM_ENT   50000
#define NUM_RELC  500
#define KTOP      50
#define EMB       400
#define FEAT      1000
#define N_NODES   50500
#define N_EDGES   400000
#define BATCH     4096
#define RELM1     499     // NUM_REL - 1

// padded GEMM dims
#define KP   1024         // FEAT padded to mult of 64
#define MP   50560        // N_NODES padded to 395*128
#define NP   512          // EMB padded to mult of 128

#define NB_SCAN ((N_NODES + 255) / 256)   // 198
#define NB_HIST ((N_EDGES + 255) / 256)   // 1563

typedef __attribute__((ext_vector_type(8))) short short8;
typedef __attribute__((ext_vector_type(4))) float f32x4;

__device__ __forceinline__ ushort f2bf(float x) {
    __hip_bfloat16 h = __float2bfloat16(x);
    return *reinterpret_cast<ushort*>(&h);
}
__device__ __forceinline__ float bflo(uint u) { return __uint_as_float(u << 16); }
__device__ __forceinline__ float bfhi(uint u) { return __uint_as_float(u & 0xffff0000u); }

// =================== mega1: copy_convert | prep | score ======================
// blocks [0, NCC): temp = nf (f32) and Abf = bf16(nf) padded  (grid-stride)
// then: logits | transpose Wa | transpose W1 | hist | small CSR | score(1024)
#define NCC      4096
#define PB_LOG   RELM1                      // 499 logits blocks
#define PB_TWA   (PB_LOG + 256)             // 16x16 tiles of Wa
#define PB_TW1   (PB_TWA + 128)             // 16x8 tiles of W1
#define PB_HIST  (PB_TW1 + NB_HIST)
#define PB_SMALL (PB_HIST + 1)
#define PB_TOTAL (PB_SMALL + BATCH / 4)     // + 1024 score blocks
__global__ void mega1_kernel(const float* __restrict__ nf, float* __restrict__ temp,
                             ushort* __restrict__ Abf,
                             const float* __restrict__ Wp, const float* __restrict__ bp,
                             float* __restrict__ logits,
                             const float* __restrict__ Wa, ushort* __restrict__ Watbf,
                             const float* __restrict__ W1, ushort* __restrict__ Btbf,
                             const int* __restrict__ edge_index, int* __restrict__ cnt,
                             const int* __restrict__ ra_edge, float* __restrict__ dinv_s,
                             int* __restrict__ offs_sm, int* __restrict__ es_sm,
                             const float* __restrict__ ent, const float* __restrict__ rel,
                             const int* __restrict__ r_idx, const int* __restrict__ e1_idx,
                             const int* __restrict__ e2_idx, const float* __restrict__ conv_w,
                             const float* __restrict__ conv_b, const float* __restrict__ fc_w,
                             const float* __restrict__ fc_b, float* __restrict__ out) {
    __shared__ float tile[64][65];
    int blk = blockIdx.x, t = threadIdx.x;
    if (blk < NCC) {
        size_t idx = (size_t)blk * 256 + t;
        size_t stride = (size_t)NCC * 256;
        size_t total = (size_t)MP * KP / 8;
        for (; idx < total; idx += stride) {
            int row = (int)(idx >> 7);
            int kb  = (int)(idx & 127);
            if (row < N_NODES && kb < 125) {
                size_t off = (size_t)row * FEAT + kb * 8;
                float4 a = *(const float4*)&nf[off];
                float4 b = *(const float4*)&nf[off + 4];
                *(float4*)&temp[off]     = a;
                *(float4*)&temp[off + 4] = b;
                ushort v[8];
                v[0] = f2bf(a.x); v[1] = f2bf(a.y); v[2] = f2bf(a.z); v[3] = f2bf(a.w);
                v[4] = f2bf(b.x); v[5] = f2bf(b.y); v[6] = f2bf(b.z); v[7] = f2bf(b.w);
                *(uint4*)&Abf[idx * 8] = *(uint4*)v;
            } else {
                uint4 z = {0u, 0u, 0u, 0u};
                *(uint4*)&Abf[idx * 8] = z;
            }
        }
        return;
    }
    int b = blk - NCC;
    if (b < PB_LOG) {
        float* red = &tile[0][0];
        float s = 0.f;
        for (int k = t; k < FEAT; k += 256) s += nf[(size_t)b * FEAT + k] * Wp[k];
        red[t] = s; __syncthreads();
        for (int st = 128; st > 0; st >>= 1) { if (t < st) red[t] += red[t + st]; __syncthreads(); }
        if (t == 0) logits[b] = red[0] + bp[0];
    } else if (b < PB_TW1) {
        const float* src; ushort* dst; int K, N, bb;
        if (b < PB_TWA) { bb = b - PB_LOG; src = Wa; dst = Watbf; K = FEAT; N = FEAT; }
        else            { bb = b - PB_TWA; src = W1; dst = Btbf;  K = FEAT; N = EMB;  }
        int k0 = (bb & 15) * 64, n0 = (bb >> 4) * 64;
        int tx = t & 63, ty = t >> 6;
        for (int i = ty; i < 64; i += 4) {
            int k = k0 + i, n = n0 + tx;
            tile[i][tx] = (k < K && n < N) ? src[(size_t)k * N + n] : 0.f;
        }
        __syncthreads();
        for (int i = ty; i < 64; i += 4) {
            int n = n0 + i, k = k0 + tx;
            dst[(size_t)n * KP + k] = f2bf(tile[tx][i]);
        }
    } else if (b < PB_HIST) {
        int e = (b - PB_TW1) * 256 + t;
        if (e < N_EDGES) atomicAdd(&cnt[edge_index[N_EDGES + e]], 1);
    } else if (b < PB_SMALL) {
        __shared__ int c[128];
        __shared__ int o50[64];
        __shared__ int cur[64];
        if (t < 128) c[t] = 0;
        if (t < 64)  cur[t] = 0;
        __syncthreads();
        for (int e = t; e < 2000; e += 256) atomicAdd(&c[ra_edge[2000 + e]], 1);
        __syncthreads();
        if (t < 2 * KTOP) dinv_s[t] = rsqrtf((float)c[t] + 1.0f);
        if (t == 0) {
            int run = 0;
            for (int j = 0; j < KTOP; j++) { o50[j] = run; run += c[KTOP + j]; }
            o50[KTOP] = run;
        }
        __syncthreads();
        if (t < KTOP + 1) offs_sm[t] = o50[t];
        for (int e = t; e < 2000; e += 256) {
            int dst = ra_edge[2000 + e];
            if (dst >= KTOP) {
                int pos = o50[dst - KTOP] + atomicAdd(&cur[dst - KTOP], 1);
                es_sm[pos] = ra_edge[e];
            }
        }
    } else {
        // ---- ConvE-ish scoring (pure-input, runs early) ----
        float* cw = &tile[0][0];
        float* cb = cw + 24;
        if (t < 24) cw[t] = conv_w[t];
        if (t < 8)  cb[t] = conv_b[t];
        __syncthreads();
        int wave = t >> 6, lane = t & 63;
        int bb = (b - PB_SMALL) * 4 + wave;
        if (bb >= BATCH) return;
        const float* r  = rel + (size_t)r_idx[bb] * EMB;
        const float* e1 = ent + (size_t)e1_idx[bb] * EMB;
        const float* e2 = ent + (size_t)e2_idx[bb] * EMB;
        float partial = 0.f;
        for (int p = lane; p < EMB; p += 64) {
            float c0 = r[p], c1 = e1[p], c2 = e2[p];
            for (int g = 0; g < 4; g++) {
                float h0 = c0 * cw[(2 * g) * 3 + 0] + c1 * cw[(2 * g) * 3 + 1] + c2 * cw[(2 * g) * 3 + 2] + cb[2 * g];
                float h1 = c0 * cw[(2 * g + 1) * 3 + 0] + c1 * cw[(2 * g + 1) * 3 + 1] + c2 * cw[(2 * g + 1) * 3 + 2] + cb[2 * g + 1];
                partial += fmaxf(h0, h1) * fc_w[g * EMB + p];
            }
        }
        for (int off = 32; off > 0; off >>= 1) partial += __shfl_down(partial, off, 64);
        if (lane == 0) out[bb] = partial + fc_b[0];
    }
}

// =================== mega2: build_rabf (local topk) | scan_blocks ============
__global__ void mega2_kernel(const float* __restrict__ logits,
                             const float* __restrict__ anchor, const float* __restrict__ nf,
                             ushort* __restrict__ rabf,
                             int* __restrict__ idxbuf, float* __restrict__ probsel,
                             const int* __restrict__ cnt, int* __restrict__ offs,
                             int* __restrict__ partials, float* __restrict__ dinv) {
    int blk = blockIdx.x, t = threadIdx.x;
    if (blk < 128) {
        __shared__ float l[RELM1];
        __shared__ float p[RELM1];
        __shared__ int   fl[RELM1];
        __shared__ float red[256];
        __shared__ int   pick;
        __shared__ float pickp;
        int r = blk;
        float v1 = (t < RELM1) ? logits[t] : -1e30f;
        float v2 = (t + 256 < RELM1) ? logits[t + 256] : -1e30f;
        if (t < RELM1) l[t] = v1;
        if (t + 256 < RELM1) l[t + 256] = v2;
        red[t] = fmaxf(v1, v2); __syncthreads();
        for (int s = 128; s > 0; s >>= 1) { if (t < s) red[t] = fmaxf(red[t], red[t + s]); __syncthreads(); }
        float m = red[0]; __syncthreads();
        float e1 = (t < RELM1) ? expf(v1 - m) : 0.f;
        float e2 = (t + 256 < RELM1) ? expf(v2 - m) : 0.f;
        red[t] = e1 + e2; __syncthreads();
        for (int s = 128; s > 0; s >>= 1) { if (t < s) red[t] += red[t + s]; __syncthreads(); }
        float denom = red[0];
        if (t < RELM1) p[t] = e1 / denom;
        if (t + 256 < RELM1) p[t + 256] = e2 / denom;
        __syncthreads();
        #pragma unroll
        for (int h = 0; h < 2; h++) {
            int i = t + h * 256;
            if (i < RELM1) {
                float li = l[i]; int c = 0;
                for (int j = 0; j < RELM1; j++) {
                    float lj = l[j];
                    c += (lj > li) || (lj == li && j < i);
                }
                fl[i] = (c < KTOP) ? 1 : 0;
            }
        }
        __syncthreads();
        if (t == 0) pick = -1;
        __syncthreads();
        int want = r - KTOP;
        #pragma unroll
        for (int h = 0; h < 2; h++) {
            int i = t + h * 256;
            if (i < RELM1 && fl[i]) {
                int rank = 0;
                for (int j = 0; j < i; j++) rank += fl[j];
                if (r == 0) { idxbuf[rank] = i; probsel[rank] = p[i]; }
                if (rank == want) { pick = i; pickp = p[i]; }
            }
        }
        __syncthreads();
        const float* src = nullptr; float scale = 1.f;
        if (r < KTOP) { src = anchor + (size_t)r * FEAT; }
        else if (r < 2 * KTOP) { src = nf + (size_t)pick * FEAT; scale = pickp; }
        for (int k = t; k < KP; k += 256) {
            float v = (src != nullptr && k < FEAT) ? src[k] * scale : 0.f;
            rabf[(size_t)r * KP + k] = f2bf(v);
        }
    } else {
        __shared__ int s[256];
        int b = blk - 128;
        int i = b * 256 + t;
        int v = (i < N_NODES) ? cnt[i] : 0;
        if (i < N_NODES) dinv[i] = rsqrtf((float)v + 1.0f);
        s[t] = v; __syncthreads();
        for (int off = 1; off < 256; off <<= 1) {
            int add = (t >= off) ? s[t - off] : 0;
            __syncthreads();
            s[t] += add;
            __syncthreads();
        }
        if (i < N_NODES) offs[i] = s[t] - v;
        if (t == 255) partials[b] = s[t];
    }
}

// every block redundantly scans the 198 partials (L2-hot), applies its carry
__global__ void scan_carry_add(int* __restrict__ offs, const int* __restrict__ partials) {
    __shared__ int s[256];
    int b = blockIdx.x, t = threadIdx.x;
    int v = (t < NB_SCAN) ? partials[t] : 0;
    s[t] = v; __syncthreads();
    for (int off = 1; off < 256; off <<= 1) {
        int add = (t >= off) ? s[t - off] : 0;
        __syncthreads();
        s[t] += add;
        __syncthreads();
    }
    int carry = (b == 0) ? 0 : s[b - 1];
    int i = b * 256 + t;
    if (i < N_NODES && carry) offs[i] += carry;
}

// =================== gemm body (device fn, shared by mega3 branches) =========
template <typename OutT, bool PACK5>
__device__ __forceinline__ void gemm_body(const ushort* __restrict__ A,
                                          const ushort* __restrict__ Bt,
                                          OutT* __restrict__ C,
                                          int M, int N, int ldc,
                                          int orig, int nwg,
                                          ushort* As, ushort* Bs, int t) {
    int q = nwg >> 3, r8 = nwg & 7;
    int xcd = orig & 7;
    int wgid = (xcd < r8 ? xcd * (q + 1) : r8 * (q + 1) + (xcd - r8) * q) + (orig >> 3);
    int ntiles = PACK5 ? 3 : ((N + 127) >> 7);
    int n0 = (wgid % ntiles) * 128;
    int m0 = (wgid / ntiles) * 128;

    int srow = t >> 3;
    int kbx  = (t & 7) ^ (srow & 7);
    int lane = t & 63;
    int wv   = t >> 6;
    int wr   = wv >> 1, wc = wv & 1;
    int l15  = lane & 15, lhi = lane >> 4;

    f32x4 acc[4][5];
    #pragma unroll
    for (int m = 0; m < 4; m++)
        #pragma unroll
        for (int n = 0; n < 5; n++) acc[m][n] = (f32x4){0.f, 0.f, 0.f, 0.f};

    for (int kt = 0; kt < KP / 64; kt++) {
        int k0 = kt * 64;
        #pragma unroll
        for (int r = 0; r < 4; r++) {
            int row = r * 32 + srow;
            const ushort* ga = A  + (size_t)(m0 + row) * KP + k0 + kbx * 8;
            const ushort* gb = Bt + (size_t)(n0 + row) * KP + k0 + kbx * 8;
            ushort* la = &As[(size_t)row * 64 + (t & 7) * 8];
            ushort* lb = &Bs[(size_t)row * 64 + (t & 7) * 8];
            __builtin_amdgcn_global_load_lds(
                (const __attribute__((address_space(1))) unsigned int*)ga,
                (__attribute__((address_space(3))) unsigned int*)la, 16, 0, 0);
            __builtin_amdgcn_global_load_lds(
                (const __attribute__((address_space(1))) unsigned int*)gb,
                (__attribute__((address_space(3))) unsigned int*)lb, 16, 0, 0);
        }
        if (PACK5) {
            if (n0 == 256 && t < 128) {
                int row = 128 + srow;
                const ushort* gb = Bt + (size_t)(n0 + row) * KP + k0 + kbx * 8;
                ushort* lb = &Bs[(size_t)row * 64 + (t & 7) * 8];
                __builtin_amdgcn_global_load_lds(
                    (const __attribute__((address_space(1))) unsigned int*)gb,
                    (__attribute__((address_space(3))) unsigned int*)lb, 16, 0, 0);
            }
        }
        __syncthreads();

        #pragma unroll
        for (int ks = 0; ks < 2; ks++) {
            int cswz = ((ks * 64 + lhi * 16) ^ ((lane & 7) << 4)) >> 1;
            short8 af[4], bfr[5];
            #pragma unroll
            for (int m = 0; m < 4; m++) {
                int rowl = wr * 64 + m * 16 + l15;
                af[m] = *(const short8*)&As[rowl * 64 + cswz];
            }
            #pragma unroll
            for (int n = 0; n < 5; n++) {
                bool valid = PACK5 ? ((n < 4) || (wc == 1 && n0 == 256))
                                   : ((n < 4) && (n0 + wc * 64 + n * 16 < N));
                if (valid) {
                    int rowl = wc * 64 + n * 16 + l15;
                    bfr[n] = *(const short8*)&Bs[rowl * 64 + cswz];
                }
            }
            #pragma unroll
            for (int m = 0; m < 4; m++)
                #pragma unroll
                for (int n = 0; n < 5; n++) {
                    bool valid = PACK5 ? ((n < 4) || (wc == 1 && n0 == 256))
                                       : ((n < 4) && (n0 + wc * 64 + n * 16 < N));
                    if (valid)
                        acc[m][n] = __builtin_amdgcn_mfma_f32_16x16x32_bf16(
                            af[m], bfr[n], acc[m][n], 0, 0, 0);
                }
        }
        __syncthreads();
    }

    #pragma unroll
    for (int m = 0; m < 4; m++) {
        #pragma unroll
        for (int n = 0; n < 5; n++) {
            bool valid = PACK5 ? ((n < 4) || (wc == 1 && n0 == 256))
                               : ((n < 4) && (n0 + wc * 64 + n * 16 < N));
            if (!valid) continue;
            int gc = n0 + wc * 64 + n * 16 + l15;
            if (gc >= N) continue;
            int gr0 = m0 + wr * 64 + m * 16 + lhi * 4;
            #pragma unroll
            for (int j = 0; j < 4; j++) {
                int gr = gr0 + j;
                if (gr < M) {
                    if constexpr (sizeof(OutT) == 2)
                        C[(size_t)gr * ldc + gc] = (OutT)f2bf(acc[m][n][j]);
                    else
                        C[(size_t)gr * ldc + gc] = (OutT)acc[m][n][j];
                }
            }
        }
    }
}

// =================== mega3: gemm_big | gemm_small | fill_csr =================
#define NBIG ((MP / 128) * 3)              // 1185
#define M3_GS (NBIG + 8)                   // +8 small-gemm blocks
#define M3_TOTAL (M3_GS + NB_HIST)         // +1563 fill_csr blocks
__global__ __launch_bounds__(256) void mega3_kernel(
        const ushort* __restrict__ Abf, const ushort* __restrict__ Btbf,
        ushort* __restrict__ xwb,
        const ushort* __restrict__ rabf, const ushort* __restrict__ Watbf,
        float* __restrict__ raw,
        const int* __restrict__ ei, const int* __restrict__ offs,
        int* __restrict__ cursor, const float* __restrict__ dinv,
        int* __restrict__ esrc, float* __restrict__ ecoef) {
    __shared__ ushort As[128 * 64];
    __shared__ ushort Bs[144 * 64];
    int blk = blockIdx.x, t = threadIdx.x;
    if (blk < NBIG) {
        gemm_body<ushort, true>(Abf, Btbf, xwb, N_NODES, EMB, EMB, blk, NBIG, As, Bs, t);
    } else if (blk < M3_GS) {
        gemm_body<float, false>(rabf, Watbf, raw, 2 * KTOP, FEAT, FEAT, blk - NBIG, 8,
                                As, Bs, t);
    } else {
        int e = (blk - M3_GS) * 256 + t;
        if (e >= N_EDGES) return;
        int src = ei[e], dst = ei[N_EDGES + e];
        int pos = offs[dst] + atomicAdd(&cursor[dst], 1);
        esrc[pos] = src;
        ecoef[pos] = dinv[src] * dinv[dst];
    }
}

// =================== epilogue: gather_big | gather_small =====================
#define EB_GB ((N_NODES + 3) / 4)          // 12625 blocks: big gather
#define EB_TOTAL (EB_GB + KTOP)            // +50: small gather into temp
__global__ __launch_bounds__(256) void epilogue_kernel(
        const int* __restrict__ esrc, const float* __restrict__ ecoef,
        const int* __restrict__ offs, const int* __restrict__ cnt,
        const ushort* __restrict__ xwb, const float* __restrict__ dinv,
        const float* __restrict__ b1, float* __restrict__ x,
        const int* __restrict__ es_sm, const int* __restrict__ offs_sm,
        const float* __restrict__ raw, const float* __restrict__ dinv_s,
        const float* __restrict__ ba, const int* __restrict__ idxbuf,
        float* __restrict__ temp) {
    int blk = blockIdx.x, t = threadIdx.x;
    if (blk < EB_GB) {
        int wave = t >> 6, lane = t & 63;
        int dst = blk * 4 + wave;
        if (dst >= N_NODES) return;
        int start = offs[dst], deg = cnt[dst];
        bool act = lane < EMB / 8;
        float acc[8] = {};
        int j = 0;
        for (; j + 1 < deg; j += 2) {
            int s0 = esrc[start + j], s1 = esrc[start + j + 1];
            float c0 = ecoef[start + j], c1 = ecoef[start + j + 1];
            if (act) {
                uint4 u0 = *(const uint4*)(xwb + (size_t)s0 * EMB + lane * 8);
                uint4 u1 = *(const uint4*)(xwb + (size_t)s1 * EMB + lane * 8);
                acc[0] += bflo(u0.x) * c0 + bflo(u1.x) * c1;
                acc[1] += bfhi(u0.x) * c0 + bfhi(u1.x) * c1;
                acc[2] += bflo(u0.y) * c0 + bflo(u1.y) * c1;
                acc[3] += bfhi(u0.y) * c0 + bfhi(u1.y) * c1;
                acc[4] += bflo(u0.z) * c0 + bflo(u1.z) * c1;
                acc[5] += bfhi(u0.z) * c0 + bfhi(u1.z) * c1;
                acc[6] += bflo(u0.w) * c0 + bflo(u1.w) * c1;
                acc[7] += bfhi(u0.w) * c0 + bfhi(u1.w) * c1;
            }
        }
        if (j < deg) {
            int s0 = esrc[start + j];
            float c0 = ecoef[start + j];
            if (act) {
                uint4 u0 = *(const uint4*)(xwb + (size_t)s0 * EMB + lane * 8);
                acc[0] += bflo(u0.x) * c0; acc[1] += bfhi(u0.x) * c0;
                acc[2] += bflo(u0.y) * c0; acc[3] += bfhi(u0.y) * c0;
                acc[4] += bflo(u0.z) * c0; acc[5] += bfhi(u0.z) * c0;
                acc[6] += bflo(u0.w) * c0; acc[7] += bfhi(u0.w) * c0;
            }
        }
        if (!act) return;
        float d2 = dinv[dst] * dinv[dst];
        uint4 u = *(const uint4*)(xwb + (size_t)dst * EMB + lane * 8);
        const float* bp = b1 + lane * 8;
        float* xo = x + (size_t)dst * EMB + lane * 8;
        float4 o0, o1;
        o0.x = fmaxf(acc[0] + bflo(u.x) * d2 + bp[0], 0.f);
        o0.y = fmaxf(acc[1] + bfhi(u.x) * d2 + bp[1], 0.f);
        o0.z = fmaxf(acc[2] + bflo(u.y) * d2 + bp[2], 0.f);
        o0.w = fmaxf(acc[3] + bfhi(u.y) * d2 + bp[3], 0.f);
        o1.x = fmaxf(acc[4] + bflo(u.z) * d2 + bp[4], 0.f);
        o1.y = fmaxf(acc[5] + bfhi(u.z) * d2 + bp[5], 0.f);
        o1.z = fmaxf(acc[6] + bflo(u.w) * d2 + bp[6], 0.f);
        o1.w = fmaxf(acc[7] + bfhi(u.w) * d2 + bp[7], 0.f);
        *(float4*)&xo[0] = o0;
        *(float4*)&xo[4] = o1;
    } else {
        int j = blk - EB_GB;
        int r = KTOP + j;
        int start = offs_sm[j], end = offs_sm[j + 1];
        float dr = dinv_s[r];
        float acc[4] = {};
        for (int p = start; p < end; p++) {
            int src = es_sm[p];
            float cc = dinv_s[src] * dr;
            const float* rs = raw + (size_t)src * FEAT;
            #pragma unroll
            for (int qq = 0; qq < 4; qq++) {
                int k = t + qq * 256;
                if (k < FEAT) acc[qq] += rs[k] * cc;
            }
        }
        float d2 = dr * dr;
        const float* rd = raw + (size_t)r * FEAT;
        float* to = temp + (size_t)idxbuf[j] * FEAT;
        #pragma unroll
        for (int qq = 0; qq < 4; qq++) {
            int k = t + qq * 256;
            if (k < FEAT) to[k] = fmaxf(acc[qq] + rd[k] * d2 + ba[k], 0.f);
        }
    }
}

extern "C" void kernel_launch(void* const* d_in, const int* in_sizes, int n_in,
                              void* d_out, int out_size, void* d_ws, size_t ws_size,
                              hipStream_t stream) {
    const float* num_feature = (const float*)d_in[0];
    const float* anchor      = (const float*)d_in[1];
    const float* Wp          = (const float*)d_in[2];
    const float* bp          = (const float*)d_in[3];
    const float* Wa          = (const float*)d_in[4];
    const float* ba          = (const float*)d_in[5];
    const float* W1          = (const float*)d_in[6];
    const float* b1          = (const float*)d_in[7];
    const float* ent_emb     = (const float*)d_in[8];
    const float* rel_emb     = (const float*)d_in[9];
    const float* conv_w      = (const float*)d_in[10];
    const float* conv_b      = (const float*)d_in[11];
    const float* fc_w        = (const float*)d_in[12];
    const float* fc_b        = (const float*)d_in[13];
    const int*   edge_index  = (const int*)d_in[14];
    const int*   ra_edge     = (const int*)d_in[15];
    const int*   r_idx       = (const int*)d_in[16];
    const int*   e1_idx      = (const int*)d_in[17];
    const int*   e2_idx      = (const int*)d_in[18];

    float* out_score = (float*)d_out;                       // 4096
    float* out_x     = out_score + BATCH;                   // 50500*400
    float* out_temp  = out_x + (size_t)N_NODES * EMB;       // 50500*1000 floats

    // ---- all scratch in d_ws (~100 MB of ~1.13 GB) ----
    float* ws_f     = (float*)d_ws;
    float* logits   = ws_f;                          // 512
    int*   idxbuf   = (int*)(ws_f + 512);            // 64
    float* probsel  = ws_f + 576;                    // 64
    float* dinv_s   = ws_f + 640;                    // 128
    int*   offs_sm  = (int*)(ws_f + 768);            // 64
    int*   es_sm    = (int*)(ws_f + 832);            // 2048
    float* raw      = ws_f + 2880;                   // 100,000
    float* dinv     = ws_f + 102880;                 // 50,500
    ushort* rabf    = (ushort*)(ws_f + 153380);      // 128*KP ushorts  (65,536 f)
    ushort* Btbf    = (ushort*)(ws_f + 218916);      // NP*KP ushorts   (262,144 f)
    ushort* Watbf   = (ushort*)(ws_f + 481060);      // KP*KP ushorts   (524,288 f)
    int*   cnt      = (int*)(ws_f + 1005348);        // 50,500
    int*   cursor   = cnt + N_NODES;                 // 50,500
    int*   offs     = cursor + N_NODES;              // 50,500
    int*   partials = offs + N_NODES;                // 256
    int*   esrc     = partials + 256;                // 400,000
    float* ecoef    = (float*)(esrc + N_EDGES);      // 400,000
    ushort* Abf     = (ushort*)(ecoef + N_EDGES);    // MP*KP ushorts (25,886,720 f)
    ushort* xwb     = Abf + (size_t)MP * KP;         // N_NODES*EMB ushorts

    hipMemsetAsync(cnt, 0, 2 * N_NODES * sizeof(int), stream);   // cnt + cursor

    // ---- mega1: copy+convert | logits | transposes | hist | smallCSR | score
    mega1_kernel<<<PB_TOTAL + NCC, 256, 0, stream>>>(
        num_feature, out_temp, Abf, Wp, bp, logits, Wa, Watbf, W1, Btbf,
        edge_index, cnt, ra_edge, dinv_s, offs_sm, es_sm,
        ent_emb, rel_emb, r_idx, e1_idx, e2_idx, conv_w, conv_b, fc_w, fc_b,
        out_score);

    // ---- mega2: rabf rows (local topk) | scan_blocks ----
    mega2_kernel<<<128 + NB_SCAN, 256, 0, stream>>>(
        logits, anchor, num_feature, rabf, idxbuf, probsel,
        cnt, offs, partials, dinv);

    // ---- finish the scan ----
    scan_carry_add<<<NB_SCAN, 256, 0, stream>>>(offs, partials);

    // ---- mega3: big GEMM | small GEMM | fill_csr (co-scheduled) ----
    mega3_kernel<<<M3_TOTAL, 256, 0, stream>>>(
        Abf, Btbf, xwb, rabf, Watbf, raw,
        edge_index, offs, cursor, dinv, esrc, ecoef);

    // ---- epilogue: big gather | small gather -> temp ----
    epilogue_kernel<<<EB_TOTAL, 256, 0, stream>>>(
        esrc, ecoef, offs, cnt, xwb, dinv, b1, out_x,
        es_sm, offs_sm, raw, dinv_s, ba, idxbuf, out_temp);
}

// Round 15
// 369.897 us; speedup vs baseline: 1.3692x; 1.0008x over previous
//
#include <hip/hip_runtime.h>
#include <hip/hip_bf16.h>

#define NUM_ENT   50000
#define NUM_RELC  500
#define KTOP      50
#define EMB       400
#define FEAT      1000
#define N_NODES   50500
#define N_EDGES   400000
#define BATCH     4096
#define RELM1     499     // NUM_REL - 1

// padded GEMM dims
#define KP   1024         // FEAT padded to mult of 64
#define MP   50560        // N_NODES padded to 395*128
#define NP   512          // EMB padded to mult of 128

#define NB_SCAN ((N_NODES + 255) / 256)   // 198
#define NB_HIST ((N_EDGES + 255) / 256)   // 1563

typedef __attribute__((ext_vector_type(8))) short short8;
typedef __attribute__((ext_vector_type(4))) float f32x4;

__device__ __forceinline__ ushort f2bf(float x) {
    __hip_bfloat16 h = __float2bfloat16(x);
    return *reinterpret_cast<ushort*>(&h);
}
__device__ __forceinline__ float bflo(uint u) { return __uint_as_float(u << 16); }
__device__ __forceinline__ float bfhi(uint u) { return __uint_as_float(u & 0xffff0000u); }

// =================== mega1: copy_convert | prep | score ======================
#define NCC      4096
#define PB_LOG   RELM1                      // 499 logits blocks
#define PB_TWA   (PB_LOG + 256)             // 16x16 tiles of Wa
#define PB_TW1   (PB_TWA + 128)             // 16x8 tiles of W1
#define PB_HIST  (PB_TW1 + NB_HIST)
#define PB_SMALL (PB_HIST + 1)
#define PB_TOTAL (PB_SMALL + BATCH / 4)     // + 1024 score blocks
__global__ void mega1_kernel(const float* __restrict__ nf, float* __restrict__ temp,
                             ushort* __restrict__ Abf,
                             const float* __restrict__ Wp, const float* __restrict__ bp,
                             float* __restrict__ logits,
                             const float* __restrict__ Wa, ushort* __restrict__ Watbf,
                             const float* __restrict__ W1, ushort* __restrict__ Btbf,
                             const int* __restrict__ edge_index, int* __restrict__ cnt,
                             const int* __restrict__ ra_edge, float* __restrict__ dinv_s,
                             int* __restrict__ offs_sm, int* __restrict__ es_sm,
                             const float* __restrict__ ent, const float* __restrict__ rel,
                             const int* __restrict__ r_idx, const int* __restrict__ e1_idx,
                             const int* __restrict__ e2_idx, const float* __restrict__ conv_w,
                             const float* __restrict__ conv_b, const float* __restrict__ fc_w,
                             const float* __restrict__ fc_b, float* __restrict__ out) {
    __shared__ float tile[64][65];
    int blk = blockIdx.x, t = threadIdx.x;
    if (blk < NCC) {
        size_t idx = (size_t)blk * 256 + t;
        size_t stride = (size_t)NCC * 256;
        size_t total = (size_t)MP * KP / 8;
        for (; idx < total; idx += stride) {
            int row = (int)(idx >> 7);
            int kb  = (int)(idx & 127);
            if (row < N_NODES && kb < 125) {
                size_t off = (size_t)row * FEAT + kb * 8;
                float4 a = *(const float4*)&nf[off];
                float4 b = *(const float4*)&nf[off + 4];
                *(float4*)&temp[off]     = a;
                *(float4*)&temp[off + 4] = b;
                ushort v[8];
                v[0] = f2bf(a.x); v[1] = f2bf(a.y); v[2] = f2bf(a.z); v[3] = f2bf(a.w);
                v[4] = f2bf(b.x); v[5] = f2bf(b.y); v[6] = f2bf(b.z); v[7] = f2bf(b.w);
                *(uint4*)&Abf[idx * 8] = *(uint4*)v;
            } else {
                uint4 z = {0u, 0u, 0u, 0u};
                *(uint4*)&Abf[idx * 8] = z;
            }
        }
        return;
    }
    int b = blk - NCC;
    if (b < PB_LOG) {
        float* red = &tile[0][0];
        float s = 0.f;
        for (int k = t; k < FEAT; k += 256) s += nf[(size_t)b * FEAT + k] * Wp[k];
        red[t] = s; __syncthreads();
        for (int st = 128; st > 0; st >>= 1) { if (t < st) red[t] += red[t + st]; __syncthreads(); }
        if (t == 0) logits[b] = red[0] + bp[0];
    } else if (b < PB_TW1) {
        const float* src; ushort* dst; int K, N, bb;
        if (b < PB_TWA) { bb = b - PB_LOG; src = Wa; dst = Watbf; K = FEAT; N = FEAT; }
        else            { bb = b - PB_TWA; src = W1; dst = Btbf;  K = FEAT; N = EMB;  }
        int k0 = (bb & 15) * 64, n0 = (bb >> 4) * 64;
        int tx = t & 63, ty = t >> 6;
        for (int i = ty; i < 64; i += 4) {
            int k = k0 + i, n = n0 + tx;
            tile[i][tx] = (k < K && n < N) ? src[(size_t)k * N + n] : 0.f;
        }
        __syncthreads();
        for (int i = ty; i < 64; i += 4) {
            int n = n0 + i, k = k0 + tx;
            dst[(size_t)n * KP + k] = f2bf(tile[tx][i]);
        }
    } else if (b < PB_HIST) {
        int e = (b - PB_TW1) * 256 + t;
        if (e < N_EDGES) atomicAdd(&cnt[edge_index[N_EDGES + e]], 1);
    } else if (b < PB_SMALL) {
        __shared__ int c[128];
        __shared__ int o50[64];
        __shared__ int cur[64];
        if (t < 128) c[t] = 0;
        if (t < 64)  cur[t] = 0;
        __syncthreads();
        for (int e = t; e < 2000; e += 256) atomicAdd(&c[ra_edge[2000 + e]], 1);
        __syncthreads();
        if (t < 2 * KTOP) dinv_s[t] = rsqrtf((float)c[t] + 1.0f);
        if (t == 0) {
            int run = 0;
            for (int j = 0; j < KTOP; j++) { o50[j] = run; run += c[KTOP + j]; }
            o50[KTOP] = run;
        }
        __syncthreads();
        if (t < KTOP + 1) offs_sm[t] = o50[t];
        for (int e = t; e < 2000; e += 256) {
            int dst = ra_edge[2000 + e];
            if (dst >= KTOP) {
                int pos = o50[dst - KTOP] + atomicAdd(&cur[dst - KTOP], 1);
                es_sm[pos] = ra_edge[e];
            }
        }
    } else {
        // ---- ConvE-ish scoring (pure-input, runs early) ----
        float* cw = &tile[0][0];
        float* cb = cw + 24;
        if (t < 24) cw[t] = conv_w[t];
        if (t < 8)  cb[t] = conv_b[t];
        __syncthreads();
        int wave = t >> 6, lane = t & 63;
        int bb = (b - PB_SMALL) * 4 + wave;
        if (bb >= BATCH) return;
        const float* r  = rel + (size_t)r_idx[bb] * EMB;
        const float* e1 = ent + (size_t)e1_idx[bb] * EMB;
        const float* e2 = ent + (size_t)e2_idx[bb] * EMB;
        float partial = 0.f;
        for (int p = lane; p < EMB; p += 64) {
            float c0 = r[p], c1 = e1[p], c2 = e2[p];
            for (int g = 0; g < 4; g++) {
                float h0 = c0 * cw[(2 * g) * 3 + 0] + c1 * cw[(2 * g) * 3 + 1] + c2 * cw[(2 * g) * 3 + 2] + cb[2 * g];
                float h1 = c0 * cw[(2 * g + 1) * 3 + 0] + c1 * cw[(2 * g + 1) * 3 + 1] + c2 * cw[(2 * g + 1) * 3 + 2] + cb[2 * g + 1];
                partial += fmaxf(h0, h1) * fc_w[g * EMB + p];
            }
        }
        for (int off = 32; off > 0; off >>= 1) partial += __shfl_down(partial, off, 64);
        if (lane == 0) out[bb] = partial + fc_b[0];
    }
}

// =================== mega2: build_rabf (local topk) | scan_blocks ============
// scan blocks now write BLOCK-LOCAL exclusive offsets + per-block totals only;
// consumers recompute the 198-partials prefix in LDS (no carry-add pass).
__global__ void mega2_kernel(const float* __restrict__ logits,
                             const float* __restrict__ anchor, const float* __restrict__ nf,
                             ushort* __restrict__ rabf,
                             int* __restrict__ idxbuf, float* __restrict__ probsel,
                             const int* __restrict__ cnt, int* __restrict__ offs,
                             int* __restrict__ partials, float* __restrict__ dinv) {
    int blk = blockIdx.x, t = threadIdx.x;
    if (blk < 128) {
        __shared__ float l[RELM1];
        __shared__ float p[RELM1];
        __shared__ int   fl[RELM1];
        __shared__ float red[256];
        __shared__ int   pick;
        __shared__ float pickp;
        int r = blk;
        float v1 = (t < RELM1) ? logits[t] : -1e30f;
        float v2 = (t + 256 < RELM1) ? logits[t + 256] : -1e30f;
        if (t < RELM1) l[t] = v1;
        if (t + 256 < RELM1) l[t + 256] = v2;
        red[t] = fmaxf(v1, v2); __syncthreads();
        for (int s = 128; s > 0; s >>= 1) { if (t < s) red[t] = fmaxf(red[t], red[t + s]); __syncthreads(); }
        float m = red[0]; __syncthreads();
        float e1 = (t < RELM1) ? expf(v1 - m) : 0.f;
        float e2 = (t + 256 < RELM1) ? expf(v2 - m) : 0.f;
        red[t] = e1 + e2; __syncthreads();
        for (int s = 128; s > 0; s >>= 1) { if (t < s) red[t] += red[t + s]; __syncthreads(); }
        float denom = red[0];
        if (t < RELM1) p[t] = e1 / denom;
        if (t + 256 < RELM1) p[t + 256] = e2 / denom;
        __syncthreads();
        #pragma unroll
        for (int h = 0; h < 2; h++) {
            int i = t + h * 256;
            if (i < RELM1) {
                float li = l[i]; int c = 0;
                for (int j = 0; j < RELM1; j++) {
                    float lj = l[j];
                    c += (lj > li) || (lj == li && j < i);
                }
                fl[i] = (c < KTOP) ? 1 : 0;
            }
        }
        __syncthreads();
        if (t == 0) pick = -1;
        __syncthreads();
        int want = r - KTOP;
        #pragma unroll
        for (int h = 0; h < 2; h++) {
            int i = t + h * 256;
            if (i < RELM1 && fl[i]) {
                int rank = 0;
                for (int j = 0; j < i; j++) rank += fl[j];
                if (r == 0) { idxbuf[rank] = i; probsel[rank] = p[i]; }
                if (rank == want) { pick = i; pickp = p[i]; }
            }
        }
        __syncthreads();
        const float* src = nullptr; float scale = 1.f;
        if (r < KTOP) { src = anchor + (size_t)r * FEAT; }
        else if (r < 2 * KTOP) { src = nf + (size_t)pick * FEAT; scale = pickp; }
        for (int k = t; k < KP; k += 256) {
            float v = (src != nullptr && k < FEAT) ? src[k] * scale : 0.f;
            rabf[(size_t)r * KP + k] = f2bf(v);
        }
    } else {
        __shared__ int s[256];
        int b = blk - 128;
        int i = b * 256 + t;
        int v = (i < N_NODES) ? cnt[i] : 0;
        if (i < N_NODES) dinv[i] = rsqrtf((float)v + 1.0f);
        s[t] = v; __syncthreads();
        for (int off = 1; off < 256; off <<= 1) {
            int add = (t >= off) ? s[t - off] : 0;
            __syncthreads();
            s[t] += add;
            __syncthreads();
        }
        if (i < N_NODES) offs[i] = s[t] - v;   // block-local exclusive offset
        if (t == 255) partials[b] = s[t];
    }
}

// ---- helper: inclusive scan of the 198 partials into LDS (per consumer blk) -
__device__ __forceinline__ void scan_partials_lds(const int* __restrict__ partials,
                                                  int* s, int t) {
    int v = (t < NB_SCAN) ? partials[t] : 0;
    s[t] = v; __syncthreads();
    for (int off = 1; off < 256; off <<= 1) {
        int add = (t >= off) ? s[t - off] : 0;
        __syncthreads();
        s[t] += add;
        __syncthreads();
    }
    // s[i] = inclusive sum; base(block b) = (b==0)?0:s[b-1]
}

// =================== gemm body (device fn, shared by mega3 branches) =========
template <typename OutT, bool PACK5>
__device__ __forceinline__ void gemm_body(const ushort* __restrict__ A,
                                          const ushort* __restrict__ Bt,
                                          OutT* __restrict__ C,
                                          int M, int N, int ldc,
                                          int orig, int nwg,
                                          ushort* As, ushort* Bs, int t) {
    int q = nwg >> 3, r8 = nwg & 7;
    int xcd = orig & 7;
    int wgid = (xcd < r8 ? xcd * (q + 1) : r8 * (q + 1) + (xcd - r8) * q) + (orig >> 3);
    int ntiles = PACK5 ? 3 : ((N + 127) >> 7);
    int n0 = (wgid % ntiles) * 128;
    int m0 = (wgid / ntiles) * 128;

    int srow = t >> 3;
    int kbx  = (t & 7) ^ (srow & 7);
    int lane = t & 63;
    int wv   = t >> 6;
    int wr   = wv >> 1, wc = wv & 1;
    int l15  = lane & 15, lhi = lane >> 4;

    f32x4 acc[4][5];
    #pragma unroll
    for (int m = 0; m < 4; m++)
        #pragma unroll
        for (int n = 0; n < 5; n++) acc[m][n] = (f32x4){0.f, 0.f, 0.f, 0.f};

    for (int kt = 0; kt < KP / 64; kt++) {
        int k0 = kt * 64;
        #pragma unroll
        for (int r = 0; r < 4; r++) {
            int row = r * 32 + srow;
            const ushort* ga = A  + (size_t)(m0 + row) * KP + k0 + kbx * 8;
            const ushort* gb = Bt + (size_t)(n0 + row) * KP + k0 + kbx * 8;
            ushort* la = &As[(size_t)row * 64 + (t & 7) * 8];
            ushort* lb = &Bs[(size_t)row * 64 + (t & 7) * 8];
            __builtin_amdgcn_global_load_lds(
                (const __attribute__((address_space(1))) unsigned int*)ga,
                (__attribute__((address_space(3))) unsigned int*)la, 16, 0, 0);
            __builtin_amdgcn_global_load_lds(
                (const __attribute__((address_space(1))) unsigned int*)gb,
                (__attribute__((address_space(3))) unsigned int*)lb, 16, 0, 0);
        }
        if (PACK5) {
            if (n0 == 256 && t < 128) {
                int row = 128 + srow;
                const ushort* gb = Bt + (size_t)(n0 + row) * KP + k0 + kbx * 8;
                ushort* lb = &Bs[(size_t)row * 64 + (t & 7) * 8];
                __builtin_amdgcn_global_load_lds(
                    (const __attribute__((address_space(1))) unsigned int*)gb,
                    (__attribute__((address_space(3))) unsigned int*)lb, 16, 0, 0);
            }
        }
        __syncthreads();

        #pragma unroll
        for (int ks = 0; ks < 2; ks++) {
            int cswz = ((ks * 64 + lhi * 16) ^ ((lane & 7) << 4)) >> 1;
            short8 af[4], bfr[5];
            #pragma unroll
            for (int m = 0; m < 4; m++) {
                int rowl = wr * 64 + m * 16 + l15;
                af[m] = *(const short8*)&As[rowl * 64 + cswz];
            }
            #pragma unroll
            for (int n = 0; n < 5; n++) {
                bool valid = PACK5 ? ((n < 4) || (wc == 1 && n0 == 256))
                                   : ((n < 4) && (n0 + wc * 64 + n * 16 < N));
                if (valid) {
                    int rowl = wc * 64 + n * 16 + l15;
                    bfr[n] = *(const short8*)&Bs[rowl * 64 + cswz];
                }
            }
            #pragma unroll
            for (int m = 0; m < 4; m++)
                #pragma unroll
                for (int n = 0; n < 5; n++) {
                    bool valid = PACK5 ? ((n < 4) || (wc == 1 && n0 == 256))
                                       : ((n < 4) && (n0 + wc * 64 + n * 16 < N));
                    if (valid)
                        acc[m][n] = __builtin_amdgcn_mfma_f32_16x16x32_bf16(
                            af[m], bfr[n], acc[m][n], 0, 0, 0);
                }
        }
        __syncthreads();
    }

    #pragma unroll
    for (int m = 0; m < 4; m++) {
        #pragma unroll
        for (int n = 0; n < 5; n++) {
            bool valid = PACK5 ? ((n < 4) || (wc == 1 && n0 == 256))
                               : ((n < 4) && (n0 + wc * 64 + n * 16 < N));
            if (!valid) continue;
            int gc = n0 + wc * 64 + n * 16 + l15;
            if (gc >= N) continue;
            int gr0 = m0 + wr * 64 + m * 16 + lhi * 4;
            #pragma unroll
            for (int j = 0; j < 4; j++) {
                int gr = gr0 + j;
                if (gr < M) {
                    if constexpr (sizeof(OutT) == 2)
                        C[(size_t)gr * ldc + gc] = (OutT)f2bf(acc[m][n][j]);
                    else
                        C[(size_t)gr * ldc + gc] = (OutT)acc[m][n][j];
                }
            }
        }
    }
}

// =================== mega3: gemm_big | gemm_small | fill_csr =================
#define NBIG ((MP / 128) * 3)              // 1185
#define M3_GS (NBIG + 8)                   // +8 small-gemm blocks
#define M3_TOTAL (M3_GS + NB_HIST)         // +1563 fill_csr blocks
__global__ __launch_bounds__(256) void mega3_kernel(
        const ushort* __restrict__ Abf, const ushort* __restrict__ Btbf,
        ushort* __restrict__ xwb,
        const ushort* __restrict__ rabf, const ushort* __restrict__ Watbf,
        float* __restrict__ raw,
        const int* __restrict__ ei, const int* __restrict__ offs,
        int* __restrict__ cursor, const float* __restrict__ dinv,
        int* __restrict__ esrc, float* __restrict__ ecoef,
        const int* __restrict__ partials) {
    __shared__ ushort As[128 * 64];
    __shared__ ushort Bs[144 * 64];
    int blk = blockIdx.x, t = threadIdx.x;
    if (blk < NBIG) {
        gemm_body<ushort, true>(Abf, Btbf, xwb, N_NODES, EMB, EMB, blk, NBIG, As, Bs, t);
    } else if (blk < M3_GS) {
        gemm_body<float, false>(rabf, Watbf, raw, 2 * KTOP, FEAT, FEAT, blk - NBIG, 8,
                                As, Bs, t);
    } else {
        // fill_csr: recompute global segment bases from partials in LDS
        int* s = (int*)As;
        scan_partials_lds(partials, s, t);
        int e = (blk - M3_GS) * 256 + t;
        if (e >= N_EDGES) return;
        int src = ei[e], dst = ei[N_EDGES + e];
        int bsc = dst >> 8;
        int gbase = (bsc == 0) ? 0 : s[bsc - 1];
        int pos = gbase + offs[dst] + atomicAdd(&cursor[dst], 1);
        esrc[pos] = src;
        ecoef[pos] = dinv[src] * dinv[dst];
    }
}

// =================== epilogue: gather_big | gather_small =====================
#define EB_GB ((N_NODES + 3) / 4)          // 12625 blocks: big gather
#define EB_TOTAL (EB_GB + KTOP)            // +50: small gather into temp
__global__ __launch_bounds__(256) void epilogue_kernel(
        const int* __restrict__ esrc, const float* __restrict__ ecoef,
        const int* __restrict__ offs, const int* __restrict__ cnt,
        const ushort* __restrict__ xwb, const float* __restrict__ dinv,
        const float* __restrict__ b1, float* __restrict__ x,
        const int* __restrict__ es_sm, const int* __restrict__ offs_sm,
        const float* __restrict__ raw, const float* __restrict__ dinv_s,
        const float* __restrict__ ba, const int* __restrict__ idxbuf,
        float* __restrict__ temp, const int* __restrict__ partials) {
    __shared__ int sb[256];
    int blk = blockIdx.x, t = threadIdx.x;
    if (blk < EB_GB) {
        // segment bases from partials (uniform work, before any divergence)
        scan_partials_lds(partials, sb, t);
        int wave = t >> 6, lane = t & 63;
        int dst = blk * 4 + wave;
        if (dst >= N_NODES) return;
        int bsc = dst >> 8;
        int gbase = (bsc == 0) ? 0 : sb[bsc - 1];
        int start = gbase + offs[dst], deg = cnt[dst];
        bool act = lane < EMB / 8;
        float acc[8] = {};
        int j = 0;
        for (; j + 1 < deg; j += 2) {
            int s0 = esrc[start + j], s1 = esrc[start + j + 1];
            float c0 = ecoef[start + j], c1 = ecoef[start + j + 1];
            if (act) {
                uint4 u0 = *(const uint4*)(xwb + (size_t)s0 * EMB + lane * 8);
                uint4 u1 = *(const uint4*)(xwb + (size_t)s1 * EMB + lane * 8);
                acc[0] += bflo(u0.x) * c0 + bflo(u1.x) * c1;
                acc[1] += bfhi(u0.x) * c0 + bfhi(u1.x) * c1;
                acc[2] += bflo(u0.y) * c0 + bflo(u1.y) * c1;
                acc[3] += bfhi(u0.y) * c0 + bfhi(u1.y) * c1;
                acc[4] += bflo(u0.z) * c0 + bflo(u1.z) * c1;
                acc[5] += bfhi(u0.z) * c0 + bfhi(u1.z) * c1;
                acc[6] += bflo(u0.w) * c0 + bflo(u1.w) * c1;
                acc[7] += bfhi(u0.w) * c0 + bfhi(u1.w) * c1;
            }
        }
        if (j < deg) {
            int s0 = esrc[start + j];
            float c0 = ecoef[start + j];
            if (act) {
                uint4 u0 = *(const uint4*)(xwb + (size_t)s0 * EMB + lane * 8);
                acc[0] += bflo(u0.x) * c0; acc[1] += bfhi(u0.x) * c0;
                acc[2] += bflo(u0.y) * c0; acc[3] += bfhi(u0.y) * c0;
                acc[4] += bflo(u0.z) * c0; acc[5] += bfhi(u0.z) * c0;
                acc[6] += bflo(u0.w) * c0; acc[7] += bfhi(u0.w) * c0;
            }
        }
        if (!act) return;
        float d2 = dinv[dst] * dinv[dst];
        uint4 u = *(const uint4*)(xwb + (size_t)dst * EMB + lane * 8);
        const float* bp = b1 + lane * 8;
        float* xo = x + (size_t)dst * EMB + lane * 8;
        float4 o0, o1;
        o0.x = fmaxf(acc[0] + bflo(u.x) * d2 + bp[0], 0.f);
        o0.y = fmaxf(acc[1] + bfhi(u.x) * d2 + bp[1], 0.f);
        o0.z = fmaxf(acc[2] + bflo(u.y) * d2 + bp[2], 0.f);
        o0.w = fmaxf(acc[3] + bfhi(u.y) * d2 + bp[3], 0.f);
        o1.x = fmaxf(acc[4] + bflo(u.z) * d2 + bp[4], 0.f);
        o1.y = fmaxf(acc[5] + bfhi(u.z) * d2 + bp[5], 0.f);
        o1.z = fmaxf(acc[6] + bflo(u.w) * d2 + bp[6], 0.f);
        o1.w = fmaxf(acc[7] + bfhi(u.w) * d2 + bp[7], 0.f);
        *(float4*)&xo[0] = o0;
        *(float4*)&xo[4] = o1;
    } else {
        int j = blk - EB_GB;
        int r = KTOP + j;
        int start = offs_sm[j], end = offs_sm[j + 1];
        float dr = dinv_s[r];
        float acc[4] = {};
        for (int p = start; p < end; p++) {
            int src = es_sm[p];
            float cc = dinv_s[src] * dr;
            const float* rs = raw + (size_t)src * FEAT;
            #pragma unroll
            for (int qq = 0; qq < 4; qq++) {
                int k = t + qq * 256;
                if (k < FEAT) acc[qq] += rs[k] * cc;
            }
        }
        float d2 = dr * dr;
        const float* rd = raw + (size_t)r * FEAT;
        float* to = temp + (size_t)idxbuf[j] * FEAT;
        #pragma unroll
        for (int qq = 0; qq < 4; qq++) {
            int k = t + qq * 256;
            if (k < FEAT) to[k] = fmaxf(acc[qq] + rd[k] * d2 + ba[k], 0.f);
        }
    }
}

extern "C" void kernel_launch(void* const* d_in, const int* in_sizes, int n_in,
                              void* d_out, int out_size, void* d_ws, size_t ws_size,
                              hipStream_t stream) {
    const float* num_feature = (const float*)d_in[0];
    const float* anchor      = (const float*)d_in[1];
    const float* Wp          = (const float*)d_in[2];
    const float* bp          = (const float*)d_in[3];
    const float* Wa          = (const float*)d_in[4];
    const float* ba          = (const float*)d_in[5];
    const float* W1          = (const float*)d_in[6];
    const float* b1          = (const float*)d_in[7];
    const float* ent_emb     = (const float*)d_in[8];
    const float* rel_emb     = (const float*)d_in[9];
    const float* conv_w      = (const float*)d_in[10];
    const float* conv_b      = (const float*)d_in[11];
    const float* fc_w        = (const float*)d_in[12];
    const float* fc_b        = (const float*)d_in[13];
    const int*   edge_index  = (const int*)d_in[14];
    const int*   ra_edge     = (const int*)d_in[15];
    const int*   r_idx       = (const int*)d_in[16];
    const int*   e1_idx      = (const int*)d_in[17];
    const int*   e2_idx      = (const int*)d_in[18];

    float* out_score = (float*)d_out;                       // 4096
    float* out_x     = out_score + BATCH;                   // 50500*400
    float* out_temp  = out_x + (size_t)N_NODES * EMB;       // 50500*1000 floats

    // ---- all scratch in d_ws (~100 MB of ~1.13 GB) ----
    float* ws_f     = (float*)d_ws;
    float* logits   = ws_f;                          // 512
    int*   idxbuf   = (int*)(ws_f + 512);            // 64
    float* probsel  = ws_f + 576;                    // 64
    float* dinv_s   = ws_f + 640;                    // 128
    int*   offs_sm  = (int*)(ws_f + 768);            // 64
    int*   es_sm    = (int*)(ws_f + 832);            // 2048
    float* raw      = ws_f + 2880;                   // 100,000
    float* dinv     = ws_f + 102880;                 // 50,500
    ushort* rabf    = (ushort*)(ws_f + 153380);      // 128*KP ushorts  (65,536 f)
    ushort* Btbf    = (ushort*)(ws_f + 218916);      // NP*KP ushorts   (262,144 f)
    ushort* Watbf   = (ushort*)(ws_f + 481060);      // KP*KP ushorts   (524,288 f)
    int*   cnt      = (int*)(ws_f + 1005348);        // 50,500
    int*   cursor   = cnt + N_NODES;                 // 50,500
    int*   offs     = cursor + N_NODES;              // 50,500
    int*   partials = offs + N_NODES;                // 256
    int*   esrc     = partials + 256;                // 400,000
    float* ecoef    = (float*)(esrc + N_EDGES);      // 400,000
    ushort* Abf     = (ushort*)(ecoef + N_EDGES);    // MP*KP ushorts (25,886,720 f)
    ushort* xwb     = Abf + (size_t)MP * KP;         // N_NODES*EMB ushorts

    hipMemsetAsync(cnt, 0, 2 * N_NODES * sizeof(int), stream);   // cnt + cursor

    // ---- mega1: copy+convert | logits | transposes | hist | smallCSR | score
    mega1_kernel<<<PB_TOTAL + NCC, 256, 0, stream>>>(
        num_feature, out_temp, Abf, Wp, bp, logits, Wa, Watbf, W1, Btbf,
        edge_index, cnt, ra_edge, dinv_s, offs_sm, es_sm,
        ent_emb, rel_emb, r_idx, e1_idx, e2_idx, conv_w, conv_b, fc_w, fc_b,
        out_score);

    // ---- mega2: rabf rows (local topk) | scan_blocks (local offsets) ----
    mega2_kernel<<<128 + NB_SCAN, 256, 0, stream>>>(
        logits, anchor, num_feature, rabf, idxbuf, probsel,
        cnt, offs, partials, dinv);

    // ---- mega3: big GEMM | small GEMM | fill_csr (local prefix recompute) ----
    mega3_kernel<<<M3_TOTAL, 256, 0, stream>>>(
        Abf, Btbf, xwb, rabf, Watbf, raw,
        edge_index, offs, cursor, dinv, esrc, ecoef, partials);

    // ---- epilogue: big gather (local prefix recompute) | small gather ----
    epilogue_kernel<<<EB_TOTAL, 256, 0, stream>>>(
        esrc, ecoef, offs, cnt, xwb, dinv, b1, out_x,
        es_sm, offs_sm, raw, dinv_s, ba, idxbuf, out_temp, partials);
}

// Round 16
// 355.931 us; speedup vs baseline: 1.4229x; 1.0392x over previous
//
#include <hip/hip_runtime.h>
#include <hip/hip_bf16.h>

#define NUM_ENT   50000
#define NUM_RELC  500
#define KTOP      50
#define EMB       400
#define FEAT      1000
#define N_NODES   50500
#define N_EDGES   400000
#define BATCH     4096
#define RELM1     499     // NUM_REL - 1

// padded GEMM dims
#define KP   1024         // FEAT padded to mult of 64
#define MP   50560        // N_NODES padded to 395*128
#define NP   512          // EMB padded to mult of 128

#define NB_SCAN ((N_NODES + 255) / 256)   // 198
#define NB_HIST ((N_EDGES + 255) / 256)   // 1563

typedef __attribute__((ext_vector_type(8))) short short8;
typedef __attribute__((ext_vector_type(4))) float f32x4;

__device__ __forceinline__ ushort f2bf(float x) {
    __hip_bfloat16 h = __float2bfloat16(x);
    return *reinterpret_cast<ushort*>(&h);
}
__device__ __forceinline__ float bflo(uint u) { return __uint_as_float(u << 16); }
__device__ __forceinline__ float bfhi(uint u) { return __uint_as_float(u & 0xffff0000u); }

// =================== mega1: copy_convert | prep | score ======================
#define NCC      4096
#define PB_LOG   RELM1                      // 499 logits blocks
#define PB_TWA   (PB_LOG + 256)             // 16x16 tiles of Wa
#define PB_TW1   (PB_TWA + 128)             // 16x8 tiles of W1
#define PB_HIST  (PB_TW1 + NB_HIST)
#define PB_SMALL (PB_HIST + 1)
#define PB_TOTAL (PB_SMALL + BATCH / 4)     // + 1024 score blocks
__global__ void mega1_kernel(const float* __restrict__ nf, float* __restrict__ temp,
                             ushort* __restrict__ Abf,
                             const float* __restrict__ Wp, const float* __restrict__ bp,
                             float* __restrict__ logits,
                             const float* __restrict__ Wa, ushort* __restrict__ Watbf,
                             const float* __restrict__ W1, ushort* __restrict__ Btbf,
                             const int* __restrict__ edge_index, int* __restrict__ cnt,
                             const int* __restrict__ ra_edge, float* __restrict__ dinv_s,
                             int* __restrict__ offs_sm, int* __restrict__ es_sm,
                             const float* __restrict__ ent, const float* __restrict__ rel,
                             const int* __restrict__ r_idx, const int* __restrict__ e1_idx,
                             const int* __restrict__ e2_idx, const float* __restrict__ conv_w,
                             const float* __restrict__ conv_b, const float* __restrict__ fc_w,
                             const float* __restrict__ fc_b, float* __restrict__ out) {
    __shared__ float tile[64][65];
    int blk = blockIdx.x, t = threadIdx.x;
    if (blk < NCC) {
        size_t idx = (size_t)blk * 256 + t;
        size_t stride = (size_t)NCC * 256;
        size_t total = (size_t)MP * KP / 8;
        for (; idx < total; idx += stride) {
            int row = (int)(idx >> 7);
            int kb  = (int)(idx & 127);
            if (row < N_NODES && kb < 125) {
                size_t off = (size_t)row * FEAT + kb * 8;
                float4 a = *(const float4*)&nf[off];
                float4 b = *(const float4*)&nf[off + 4];
                *(float4*)&temp[off]     = a;
                *(float4*)&temp[off + 4] = b;
                ushort v[8];
                v[0] = f2bf(a.x); v[1] = f2bf(a.y); v[2] = f2bf(a.z); v[3] = f2bf(a.w);
                v[4] = f2bf(b.x); v[5] = f2bf(b.y); v[6] = f2bf(b.z); v[7] = f2bf(b.w);
                *(uint4*)&Abf[idx * 8] = *(uint4*)v;
            } else {
                uint4 z = {0u, 0u, 0u, 0u};
                *(uint4*)&Abf[idx * 8] = z;
            }
        }
        return;
    }
    int b = blk - NCC;
    if (b < PB_LOG) {
        float* red = &tile[0][0];
        float s = 0.f;
        for (int k = t; k < FEAT; k += 256) s += nf[(size_t)b * FEAT + k] * Wp[k];
        red[t] = s; __syncthreads();
        for (int st = 128; st > 0; st >>= 1) { if (t < st) red[t] += red[t + st]; __syncthreads(); }
        if (t == 0) logits[b] = red[0] + bp[0];
    } else if (b < PB_TW1) {
        const float* src; ushort* dst; int K, N, bb;
        if (b < PB_TWA) { bb = b - PB_LOG; src = Wa; dst = Watbf; K = FEAT; N = FEAT; }
        else            { bb = b - PB_TWA; src = W1; dst = Btbf;  K = FEAT; N = EMB;  }
        int k0 = (bb & 15) * 64, n0 = (bb >> 4) * 64;
        int tx = t & 63, ty = t >> 6;
        for (int i = ty; i < 64; i += 4) {
            int k = k0 + i, n = n0 + tx;
            tile[i][tx] = (k < K && n < N) ? src[(size_t)k * N + n] : 0.f;
        }
        __syncthreads();
        for (int i = ty; i < 64; i += 4) {
            int n = n0 + i, k = k0 + tx;
            dst[(size_t)n * KP + k] = f2bf(tile[tx][i]);
        }
    } else if (b < PB_HIST) {
        int e = (b - PB_TW1) * 256 + t;
        if (e < N_EDGES) atomicAdd(&cnt[edge_index[N_EDGES + e]], 1);
    } else if (b < PB_SMALL) {
        __shared__ int c[128];
        __shared__ int o50[64];
        __shared__ int cur[64];
        if (t < 128) c[t] = 0;
        if (t < 64)  cur[t] = 0;
        __syncthreads();
        for (int e = t; e < 2000; e += 256) atomicAdd(&c[ra_edge[2000 + e]], 1);
        __syncthreads();
        if (t < 2 * KTOP) dinv_s[t] = rsqrtf((float)c[t] + 1.0f);
        if (t == 0) {
            int run = 0;
            for (int j = 0; j < KTOP; j++) { o50[j] = run; run += c[KTOP + j]; }
            o50[KTOP] = run;
        }
        __syncthreads();
        if (t < KTOP + 1) offs_sm[t] = o50[t];
        for (int e = t; e < 2000; e += 256) {
            int dst = ra_edge[2000 + e];
            if (dst >= KTOP) {
                int pos = o50[dst - KTOP] + atomicAdd(&cur[dst - KTOP], 1);
                es_sm[pos] = ra_edge[e];
            }
        }
    } else {
        // ---- ConvE-ish scoring (pure-input, runs early) ----
        float* cw = &tile[0][0];
        float* cb = cw + 24;
        if (t < 24) cw[t] = conv_w[t];
        if (t < 8)  cb[t] = conv_b[t];
        __syncthreads();
        int wave = t >> 6, lane = t & 63;
        int bb = (b - PB_SMALL) * 4 + wave;
        if (bb >= BATCH) return;
        const float* r  = rel + (size_t)r_idx[bb] * EMB;
        const float* e1 = ent + (size_t)e1_idx[bb] * EMB;
        const float* e2 = ent + (size_t)e2_idx[bb] * EMB;
        float partial = 0.f;
        for (int p = lane; p < EMB; p += 64) {
            float c0 = r[p], c1 = e1[p], c2 = e2[p];
            for (int g = 0; g < 4; g++) {
                float h0 = c0 * cw[(2 * g) * 3 + 0] + c1 * cw[(2 * g) * 3 + 1] + c2 * cw[(2 * g) * 3 + 2] + cb[2 * g];
                float h1 = c0 * cw[(2 * g + 1) * 3 + 0] + c1 * cw[(2 * g + 1) * 3 + 1] + c2 * cw[(2 * g + 1) * 3 + 2] + cb[2 * g + 1];
                partial += fmaxf(h0, h1) * fc_w[g * EMB + p];
            }
        }
        for (int off = 32; off > 0; off >>= 1) partial += __shfl_down(partial, off, 64);
        if (lane == 0) out[bb] = partial + fc_b[0];
    }
}

// =================== mega2: build_rabf | scan_blocks | bases =================
__global__ void mega2_kernel(const float* __restrict__ logits,
                             const float* __restrict__ anchor, const float* __restrict__ nf,
                             ushort* __restrict__ rabf,
                             int* __restrict__ idxbuf, float* __restrict__ probsel,
                             const int* __restrict__ cnt, int* __restrict__ offs,
                             int* __restrict__ partials, float* __restrict__ dinv,
                             int* __restrict__ gbases) {
    int blk = blockIdx.x, t = threadIdx.x;
    if (blk < 128) {
        __shared__ float l[RELM1];
        __shared__ float p[RELM1];
        __shared__ int   fl[RELM1];
        __shared__ float red[256];
        __shared__ int   pick;
        __shared__ float pickp;
        int r = blk;
        float v1 = (t < RELM1) ? logits[t] : -1e30f;
        float v2 = (t + 256 < RELM1) ? logits[t + 256] : -1e30f;
        if (t < RELM1) l[t] = v1;
        if (t + 256 < RELM1) l[t + 256] = v2;
        red[t] = fmaxf(v1, v2); __syncthreads();
        for (int s = 128; s > 0; s >>= 1) { if (t < s) red[t] = fmaxf(red[t], red[t + s]); __syncthreads(); }
        float m = red[0]; __syncthreads();
        float e1 = (t < RELM1) ? expf(v1 - m) : 0.f;
        float e2 = (t + 256 < RELM1) ? expf(v2 - m) : 0.f;
        red[t] = e1 + e2; __syncthreads();
        for (int s = 128; s > 0; s >>= 1) { if (t < s) red[t] += red[t + s]; __syncthreads(); }
        float denom = red[0];
        if (t < RELM1) p[t] = e1 / denom;
        if (t + 256 < RELM1) p[t + 256] = e2 / denom;
        __syncthreads();
        #pragma unroll
        for (int h = 0; h < 2; h++) {
            int i = t + h * 256;
            if (i < RELM1) {
                float li = l[i]; int c = 0;
                for (int j = 0; j < RELM1; j++) {
                    float lj = l[j];
                    c += (lj > li) || (lj == li && j < i);
                }
                fl[i] = (c < KTOP) ? 1 : 0;
            }
        }
        __syncthreads();
        if (t == 0) pick = -1;
        __syncthreads();
        int want = r - KTOP;
        #pragma unroll
        for (int h = 0; h < 2; h++) {
            int i = t + h * 256;
            if (i < RELM1 && fl[i]) {
                int rank = 0;
                for (int j = 0; j < i; j++) rank += fl[j];
                if (r == 0) { idxbuf[rank] = i; probsel[rank] = p[i]; }
                if (rank == want) { pick = i; pickp = p[i]; }
            }
        }
        __syncthreads();
        const float* src = nullptr; float scale = 1.f;
        if (r < KTOP) { src = anchor + (size_t)r * FEAT; }
        else if (r < 2 * KTOP) { src = nf + (size_t)pick * FEAT; scale = pickp; }
        for (int k = t; k < KP; k += 256) {
            float v = (src != nullptr && k < FEAT) ? src[k] * scale : 0.f;
            rabf[(size_t)r * KP + k] = f2bf(v);
        }
    } else if (blk < 128 + NB_SCAN) {
        __shared__ int s[256];
        int b = blk - 128;
        int i = b * 256 + t;
        int v = (i < N_NODES) ? cnt[i] : 0;
        if (i < N_NODES) dinv[i] = rsqrtf((float)v + 1.0f);
        s[t] = v; __syncthreads();
        for (int off = 1; off < 256; off <<= 1) {
            int add = (t >= off) ? s[t - off] : 0;
            __syncthreads();
            s[t] += add;
            __syncthreads();
        }
        if (i < N_NODES) offs[i] = s[t] - v;   // block-local exclusive offset
        if (t == 255) partials[b] = s[t];
    } else {
        // bases: exclusive prefix over per-block totals (cnt is final; recompute
        // totals by summing 256 cnt entries per scan-block — independent of
        // partials write order within this dispatch? No: partials written by
        // sibling blocks in THIS dispatch. Recompute from cnt instead (safe).
        __shared__ int s[256];
        int sum = 0;
        if (t < NB_SCAN) {
            int base = t * 256;
            for (int i = 0; i < 256; i++) {
                int idx = base + i;
                sum += (idx < N_NODES) ? cnt[idx] : 0;
            }
        }
        s[t] = sum; __syncthreads();
        for (int off = 1; off < 256; off <<= 1) {
            int add = (t >= off) ? s[t - off] : 0;
            __syncthreads();
            s[t] += add;
            __syncthreads();
        }
        if (t < NB_SCAN) gbases[t] = s[t] - sum;   // exclusive base per segment
    }
}

// =================== small gemm body (256-thread geometry) ===================
__device__ __forceinline__ void gemm_small_body(const ushort* __restrict__ A,
                                                const ushort* __restrict__ Bt,
                                                float* __restrict__ C,
                                                int M, int N, int ldc,
                                                int orig, int nwg,
                                                ushort* As, ushort* Bs, int t) {
    int ntiles = (N + 127) >> 7;
    int n0 = (orig % ntiles) * 128;
    int m0 = (orig / ntiles) * 128;

    int srow = t >> 3;
    int kbx  = (t & 7) ^ (srow & 7);
    int lane = t & 63;
    int wv   = t >> 6;
    int wr   = wv >> 1, wc = wv & 1;
    int l15  = lane & 15, lhi = lane >> 4;

    f32x4 acc[4][4];
    #pragma unroll
    for (int m = 0; m < 4; m++)
        #pragma unroll
        for (int n = 0; n < 4; n++) acc[m][n] = (f32x4){0.f, 0.f, 0.f, 0.f};

    for (int kt = 0; kt < KP / 64; kt++) {
        int k0 = kt * 64;
        #pragma unroll
        for (int r = 0; r < 4; r++) {
            int row = r * 32 + srow;
            const ushort* ga = A  + (size_t)(m0 + row) * KP + k0 + kbx * 8;
            const ushort* gb = Bt + (size_t)(n0 + row) * KP + k0 + kbx * 8;
            ushort* la = &As[(size_t)row * 64 + (t & 7) * 8];
            ushort* lb = &Bs[(size_t)row * 64 + (t & 7) * 8];
            __builtin_amdgcn_global_load_lds(
                (const __attribute__((address_space(1))) unsigned int*)ga,
                (__attribute__((address_space(3))) unsigned int*)la, 16, 0, 0);
            __builtin_amdgcn_global_load_lds(
                (const __attribute__((address_space(1))) unsigned int*)gb,
                (__attribute__((address_space(3))) unsigned int*)lb, 16, 0, 0);
        }
        __syncthreads();

        #pragma unroll
        for (int ks = 0; ks < 2; ks++) {
            int cswz = ((ks * 64 + lhi * 16) ^ ((lane & 7) << 4)) >> 1;
            short8 af[4], bfr[4];
            #pragma unroll
            for (int m = 0; m < 4; m++) {
                int rowl = wr * 64 + m * 16 + l15;
                af[m] = *(const short8*)&As[rowl * 64 + cswz];
            }
            #pragma unroll
            for (int n = 0; n < 4; n++) {
                if (n0 + wc * 64 + n * 16 < N) {
                    int rowl = wc * 64 + n * 16 + l15;
                    bfr[n] = *(const short8*)&Bs[rowl * 64 + cswz];
                }
            }
            #pragma unroll
            for (int m = 0; m < 4; m++)
                #pragma unroll
                for (int n = 0; n < 4; n++)
                    if (n0 + wc * 64 + n * 16 < N)
                        acc[m][n] = __builtin_amdgcn_mfma_f32_16x16x32_bf16(
                            af[m], bfr[n], acc[m][n], 0, 0, 0);
        }
        __syncthreads();
    }

    #pragma unroll
    for (int m = 0; m < 4; m++) {
        #pragma unroll
        for (int n = 0; n < 4; n++) {
            int gc = n0 + wc * 64 + n * 16 + l15;
            if (gc >= N) continue;
            int gr0 = m0 + wr * 64 + m * 16 + lhi * 4;
            #pragma unroll
            for (int j = 0; j < 4; j++) {
                int gr = gr0 + j;
                if (gr < M) C[(size_t)gr * ldc + gc] = acc[m][n][j];
            }
        }
    }
}

// =================== big gemm body (512 threads, BM=128 x BN=400) ============
// 8 waves (2m x 4n); col-frags per n-wave: {7,6,6,6} -> exact 400-col coverage.
// A staged ONCE per m-panel (no n-tiling).
__device__ __forceinline__ void gemm_big_body(const ushort* __restrict__ A,
                                              const ushort* __restrict__ Bt,
                                              ushort* __restrict__ C,
                                              int M, int ldc,
                                              int orig, int nwg,
                                              ushort* As, ushort* Bs, int t) {
    int q = nwg >> 3, r8 = nwg & 7;
    int xcd = orig & 7;
    int wgid = (xcd < r8 ? xcd * (q + 1) : r8 * (q + 1) + (xcd - r8) * q) + (orig >> 3);
    int m0 = wgid * 128;

    int lane = t & 63;
    int wv   = t >> 6;          // 0..7
    int wr   = wv >> 2;         // 0..1 (m half)
    int wc   = wv & 3;          // 0..3 (n quarter)
    int l15  = lane & 15, lhi = lane >> 4;
    int cbase = (wc == 0) ? 0 : 112 + (wc - 1) * 96;   // 0,112,208,304 (all %8==0)
    int nf    = (wc == 0) ? 7 : 6;

    f32x4 acc[4][7];
    #pragma unroll
    for (int m = 0; m < 4; m++)
        #pragma unroll
        for (int n = 0; n < 7; n++) acc[m][n] = (f32x4){0.f, 0.f, 0.f, 0.f};

    for (int kt = 0; kt < KP / 64; kt++) {
        int k0 = kt * 64;
        // ---- A: 128 rows x 8 chunks = 1024 chunks, 2 rounds of 512 ----
        #pragma unroll
        for (int r = 0; r < 2; r++) {
            int cid = r * 512 + t;
            int row = cid >> 3, kb = cid & 7;
            int kbx = kb ^ (row & 7);
            const ushort* ga = A + (size_t)(m0 + row) * KP + k0 + kbx * 8;
            ushort* la = &As[(size_t)row * 64 + kb * 8];
            __builtin_amdgcn_global_load_lds(
                (const __attribute__((address_space(1))) unsigned int*)ga,
                (__attribute__((address_space(3))) unsigned int*)la, 16, 0, 0);
        }
        // ---- B: 400 rows x 8 chunks = 3200 chunks, 7 rounds (last partial:
        //      3200 = 6*512 + 128 -> round 6 activates waves 0..1 only) ----
        #pragma unroll
        for (int r = 0; r < 7; r++) {
            int cid = r * 512 + t;
            if (cid < 3200) {
                int row = cid >> 3, kb = cid & 7;
                int kbx = kb ^ (row & 7);
                const ushort* gb = Bt + (size_t)row * KP + k0 + kbx * 8;
                ushort* lb = &Bs[(size_t)row * 64 + kb * 8];
                __builtin_amdgcn_global_load_lds(
                    (const __attribute__((address_space(1))) unsigned int*)gb,
                    (__attribute__((address_space(3))) unsigned int*)lb, 16, 0, 0);
            }
        }
        __syncthreads();

        #pragma unroll
        for (int ks = 0; ks < 2; ks++) {
            int cswz = ((ks * 64 + lhi * 16) ^ ((lane & 7) << 4)) >> 1;
            short8 af[4], bfr[7];
            #pragma unroll
            for (int m = 0; m < 4; m++) {
                int rowl = wr * 64 + m * 16 + l15;
                af[m] = *(const short8*)&As[rowl * 64 + cswz];
            }
            #pragma unroll
            for (int n = 0; n < 7; n++) {
                if (n < nf) {
                    int rowl = cbase + n * 16 + l15;   // rowl&7 == lane&7
                    bfr[n] = *(const short8*)&Bs[rowl * 64 + cswz];
                }
            }
            #pragma unroll
            for (int m = 0; m < 4; m++)
                #pragma unroll
                for (int n = 0; n < 7; n++)
                    if (n < nf)
                        acc[m][n] = __builtin_amdgcn_mfma_f32_16x16x32_bf16(
                            af[m], bfr[n], acc[m][n], 0, 0, 0);
        }
        __syncthreads();
    }

    #pragma unroll
    for (int m = 0; m < 4; m++) {
        #pragma unroll
        for (int n = 0; n < 7; n++) {
            if (n >= nf) continue;
            int gc = cbase + n * 16 + l15;            // always < 400
            int gr0 = m0 + wr * 64 + m * 16 + lhi * 4;
            #pragma unroll
            for (int j = 0; j < 4; j++) {
                int gr = gr0 + j;
                if (gr < M) C[(size_t)gr * ldc + gc] = f2bf(acc[m][n][j]);
            }
        }
    }
}

// =================== mega3 (512 threads): gemm_big | gemm_small | fill_csr ===
#define NBIG2    (MP / 128)                // 395
#define M3_GS    (NBIG2 + 8)               // +8 small-gemm blocks
#define NB_CSR   ((N_EDGES + 511) / 512)   // 782
#define M3_TOTAL (M3_GS + NB_CSR)
__global__ __launch_bounds__(512) void mega3_kernel(
        const ushort* __restrict__ Abf, const ushort* __restrict__ Btbf,
        ushort* __restrict__ xwb,
        const ushort* __restrict__ rabf, const ushort* __restrict__ Watbf,
        float* __restrict__ raw,
        const int* __restrict__ ei, const int* __restrict__ offs,
        int* __restrict__ cursor, const float* __restrict__ dinv,
        int* __restrict__ esrc, float* __restrict__ ecoef,
        const int* __restrict__ gbases) {
    __shared__ ushort As[128 * 64];    // 16 KB
    __shared__ ushort Bs[400 * 64];    // 51.2 KB
    int blk = blockIdx.x, t = threadIdx.x;
    if (blk < NBIG2) {
        gemm_big_body(Abf, Btbf, xwb, N_NODES, EMB, blk, NBIG2, As, Bs, t);
    } else if (blk < M3_GS) {
        // 256-thread geometry; upper half mirrors lower (identical work, safe)
        gemm_small_body(rabf, Watbf, raw, 2 * KTOP, FEAT, FEAT, blk - NBIG2, 8,
                        As, Bs, t & 255);
    } else {
        int e = (blk - M3_GS) * 512 + t;
        if (e >= N_EDGES) return;
        int src = ei[e], dst = ei[N_EDGES + e];
        int pos = gbases[dst >> 8] + offs[dst] + atomicAdd(&cursor[dst], 1);
        esrc[pos] = src;
        ecoef[pos] = dinv[src] * dinv[dst];
    }
}

// =================== epilogue: gather_big | gather_small =====================
#define EB_GB ((N_NODES + 3) / 4)          // 12625 blocks: big gather
#define EB_TOTAL (EB_GB + KTOP)            // +50: small gather into temp
__global__ __launch_bounds__(256) void epilogue_kernel(
        const int* __restrict__ esrc, const float* __restrict__ ecoef,
        const int* __restrict__ offs, const int* __restrict__ cnt,
        const ushort* __restrict__ xwb, const float* __restrict__ dinv,
        const float* __restrict__ b1, float* __restrict__ x,
        const int* __restrict__ es_sm, const int* __restrict__ offs_sm,
        const float* __restrict__ raw, const float* __restrict__ dinv_s,
        const float* __restrict__ ba, const int* __restrict__ idxbuf,
        float* __restrict__ temp, const int* __restrict__ gbases) {
    int blk = blockIdx.x, t = threadIdx.x;
    if (blk < EB_GB) {
        int wave = t >> 6, lane = t & 63;
        int dst = blk * 4 + wave;
        if (dst >= N_NODES) return;
        int start = gbases[dst >> 8] + offs[dst], deg = cnt[dst];
        bool act = lane < EMB / 8;
        float acc[8] = {};
        int j = 0;
        for (; j + 1 < deg; j += 2) {
            int s0 = esrc[start + j], s1 = esrc[start + j + 1];
            float c0 = ecoef[start + j], c1 = ecoef[start + j + 1];
            if (act) {
                uint4 u0 = *(const uint4*)(xwb + (size_t)s0 * EMB + lane * 8);
                uint4 u1 = *(const uint4*)(xwb + (size_t)s1 * EMB + lane * 8);
                acc[0] += bflo(u0.x) * c0 + bflo(u1.x) * c1;
                acc[1] += bfhi(u0.x) * c0 + bfhi(u1.x) * c1;
                acc[2] += bflo(u0.y) * c0 + bflo(u1.y) * c1;
                acc[3] += bfhi(u0.y) * c0 + bfhi(u1.y) * c1;
                acc[4] += bflo(u0.z) * c0 + bflo(u1.z) * c1;
                acc[5] += bfhi(u0.z) * c0 + bfhi(u1.z) * c1;
                acc[6] += bflo(u0.w) * c0 + bflo(u1.w) * c1;
                acc[7] += bfhi(u0.w) * c0 + bfhi(u1.w) * c1;
            }
        }
        if (j < deg) {
            int s0 = esrc[start + j];
            float c0 = ecoef[start + j];
            if (act) {
                uint4 u0 = *(const uint4*)(xwb + (size_t)s0 * EMB + lane * 8);
                acc[0] += bflo(u0.x) * c0; acc[1] += bfhi(u0.x) * c0;
                acc[2] += bflo(u0.y) * c0; acc[3] += bfhi(u0.y) * c0;
                acc[4] += bflo(u0.z) * c0; acc[5] += bfhi(u0.z) * c0;
                acc[6] += bflo(u0.w) * c0; acc[7] += bfhi(u0.w) * c0;
            }
        }
        if (!act) return;
        float d2 = dinv[dst] * dinv[dst];
        uint4 u = *(const uint4*)(xwb + (size_t)dst * EMB + lane * 8);
        const float* bp = b1 + lane * 8;
        float* xo = x + (size_t)dst * EMB + lane * 8;
        float4 o0, o1;
        o0.x = fmaxf(acc[0] + bflo(u.x) * d2 + bp[0], 0.f);
        o0.y = fmaxf(acc[1] + bfhi(u.x) * d2 + bp[1], 0.f);
        o0.z = fmaxf(acc[2] + bflo(u.y) * d2 + bp[2], 0.f);
        o0.w = fmaxf(acc[3] + bfhi(u.y) * d2 + bp[3], 0.f);
        o1.x = fmaxf(acc[4] + bflo(u.z) * d2 + bp[4], 0.f);
        o1.y = fmaxf(acc[5] + bfhi(u.z) * d2 + bp[5], 0.f);
        o1.z = fmaxf(acc[6] + bflo(u.w) * d2 + bp[6], 0.f);
        o1.w = fmaxf(acc[7] + bfhi(u.w) * d2 + bp[7], 0.f);
        *(float4*)&xo[0] = o0;
        *(float4*)&xo[4] = o1;
    } else {
        int j = blk - EB_GB;
        int r = KTOP + j;
        int start = offs_sm[j], end = offs_sm[j + 1];
        float dr = dinv_s[r];
        float acc[4] = {};
        for (int p = start; p < end; p++) {
            int src = es_sm[p];
            float cc = dinv_s[src] * dr;
            const float* rs = raw + (size_t)src * FEAT;
            #pragma unroll
            for (int qq = 0; qq < 4; qq++) {
                int k = t + qq * 256;
                if (k < FEAT) acc[qq] += rs[k] * cc;
            }
        }
        float d2 = dr * dr;
        const float* rd = raw + (size_t)r * FEAT;
        float* to = temp + (size_t)idxbuf[j] * FEAT;
        #pragma unroll
        for (int qq = 0; qq < 4; qq++) {
            int k = t + qq * 256;
            if (k < FEAT) to[k] = fmaxf(acc[qq] + rd[k] * d2 + ba[k], 0.f);
        }
    }
}

extern "C" void kernel_launch(void* const* d_in, const int* in_sizes, int n_in,
                              void* d_out, int out_size, void* d_ws, size_t ws_size,
                              hipStream_t stream) {
    const float* num_feature = (const float*)d_in[0];
    const float* anchor      = (const float*)d_in[1];
    const float* Wp          = (const float*)d_in[2];
    const float* bp          = (const float*)d_in[3];
    const float* Wa          = (const float*)d_in[4];
    const float* ba          = (const float*)d_in[5];
    const float* W1          = (const float*)d_in[6];
    const float* b1          = (const float*)d_in[7];
    const float* ent_emb     = (const float*)d_in[8];
    const float* rel_emb     = (const float*)d_in[9];
    const float* conv_w      = (const float*)d_in[10];
    const float* conv_b      = (const float*)d_in[11];
    const float* fc_w        = (const float*)d_in[12];
    const float* fc_b        = (const float*)d_in[13];
    const int*   edge_index  = (const int*)d_in[14];
    const int*   ra_edge     = (const int*)d_in[15];
    const int*   r_idx       = (const int*)d_in[16];
    const int*   e1_idx      = (const int*)d_in[17];
    const int*   e2_idx      = (const int*)d_in[18];

    float* out_score = (float*)d_out;                       // 4096
    float* out_x     = out_score + BATCH;                   // 50500*400
    float* out_temp  = out_x + (size_t)N_NODES * EMB;       // 50500*1000 floats

    // ---- all scratch in d_ws (~100 MB of ~1.13 GB) ----
    float* ws_f     = (float*)d_ws;
    float* logits   = ws_f;                          // 512
    int*   idxbuf   = (int*)(ws_f + 512);            // 64
    float* probsel  = ws_f + 576;                    // 64
    float* dinv_s   = ws_f + 640;                    // 128
    int*   offs_sm  = (int*)(ws_f + 768);            // 64
    int*   es_sm    = (int*)(ws_f + 832);            // 2048
    float* raw      = ws_f + 2880;                   // 100,000
    float* dinv     = ws_f + 102880;                 // 50,500
    ushort* rabf    = (ushort*)(ws_f + 153380);      // 128*KP ushorts  (65,536 f)
    ushort* Btbf    = (ushort*)(ws_f + 218916);      // NP*KP ushorts   (262,144 f)
    ushort* Watbf   = (ushort*)(ws_f + 481060);      // KP*KP ushorts   (524,288 f)
    int*   cnt      = (int*)(ws_f + 1005348);        // 50,500
    int*   cursor   = cnt + N_NODES;                 // 50,500
    int*   offs     = cursor + N_NODES;              // 50,500
    int*   partials = offs + N_NODES;                // 256
    int*   gbases   = partials + 256;                // 256
    int*   esrc     = gbases + 256;                  // 400,000
    float* ecoef    = (float*)(esrc + N_EDGES);      // 400,000
    ushort* Abf     = (ushort*)(ecoef + N_EDGES);    // MP*KP ushorts (25,886,720 f)
    ushort* xwb     = Abf + (size_t)MP * KP;         // N_NODES*EMB ushorts

    hipMemsetAsync(cnt, 0, 2 * N_NODES * sizeof(int), stream);   // cnt + cursor

    // ---- mega1: copy+convert | logits | transposes | hist | smallCSR | score
    mega1_kernel<<<PB_TOTAL + NCC, 256, 0, stream>>>(
        num_feature, out_temp, Abf, Wp, bp, logits, Wa, Watbf, W1, Btbf,
        edge_index, cnt, ra_edge, dinv_s, offs_sm, es_sm,
        ent_emb, rel_emb, r_idx, e1_idx, e2_idx, conv_w, conv_b, fc_w, fc_b,
        out_score);

    // ---- mega2: rabf rows (local topk) | scan_blocks | segment bases ----
    mega2_kernel<<<128 + NB_SCAN + 1, 256, 0, stream>>>(
        logits, anchor, num_feature, rabf, idxbuf, probsel,
        cnt, offs, partials, dinv, gbases);

    // ---- mega3 (512T): full-N big GEMM | small GEMM | fill_csr ----
    mega3_kernel<<<M3_TOTAL, 512, 0, stream>>>(
        Abf, Btbf, xwb, rabf, Watbf, raw,
        edge_index, offs, cursor, dinv, esrc, ecoef, gbases);

    // ---- epilogue: big gather | small gather ----
    epilogue_kernel<<<EB_TOTAL, 256, 0, stream>>>(
        esrc, ecoef, offs, cnt, xwb, dinv, b1, out_x,
        es_sm, offs_sm, raw, dinv_s, ba, idxbuf, out_temp, gbases);
}